// Round 1
// baseline (1334.975 us; speedup 1.0000x reference)
//
#include <hip/hip_runtime.h>
#include <math.h>

// ---------------------------------------------------------------------------
// WaveViT attention block, f32 baseline.
// B=16, Nsp=3136 (56x56), C=256, heads=8, hd=32, red=64, sr=2
// ---------------------------------------------------------------------------

#define B_   16
#define NSP  3136
#define C_   256
#define RED  64
#define HH   56
#define WW   56
#define H2   28
#define KVL  196   // 14*14
#define HEADS 8
#define HD   32

// ============================== generic GEMM ===============================
// C[m,n] = sum_k A[m,k] * W[n,k]  (+ epilogue)
// BM=64, BK=16, TM=4; BN/TN templated. 256 threads (16x16), grid (mt, nt, B).
// LD: 0 = row-major A (per-batch, Mb rows, stride K)
//     1 = channel-major split A: k<K1 -> A[(b*K1+k)*Mb+m], else A2[(b*(K-K1)+k-K1)*Mb+m]
//     2 = implicit im2col for 2x2 stride-2 conv on (B,256,28,28) input, Mb=196
// EPI:0 = out[(b*Mb+m)*N+n] = v + bias[n]
//     1 = out[(b*N+n)*Mb+m] = (v + bias[n]) * scale          (transposed)
//     2 = out[(b*N+n)*Mb+m] = relu(v*inv + (bb - mm*inv))    (BN+ReLU, transposed)
//     3 = kv split: n<256 -> K buf, else V buf, layout ((b*8+h)*196+m)*32+d
template<int BN, int TN, int LD, int EPI>
__global__ __launch_bounds__(256) void gemm_k(
    const float* __restrict__ A, const float* __restrict__ A2,
    const float* __restrict__ W, const float* __restrict__ bias,
    const float* __restrict__ g, const float* __restrict__ bb,
    const float* __restrict__ mm, const float* __restrict__ vv,
    float* __restrict__ out, float* __restrict__ out2,
    int Mb, int N, int K, int K1, float scale)
{
    constexpr int BM = 64, BK = 16, TM = 4;
    __shared__ float As[BK][BM];
    __shared__ float Bs[BK][BN];
    const int tid = threadIdx.x;
    const int tx = tid & 15, ty = tid >> 4;
    const int b = blockIdx.z;
    const int m0 = blockIdx.x * BM;
    const int n0 = blockIdx.y * BN;

    float acc[TM][TN];
#pragma unroll
    for (int i = 0; i < TM; ++i)
#pragma unroll
        for (int j = 0; j < TN; ++j) acc[i][j] = 0.f;

    for (int k0 = 0; k0 < K; k0 += BK) {
        // ---- stage A tile -> As[k][m]
        if constexpr (LD == 0) {
            const int r = tid >> 2, kb = (tid & 3) * 4;
            const int mg = m0 + r;
            const float* ap = A + ((size_t)b * Mb + mg) * K + k0 + kb;
#pragma unroll
            for (int i = 0; i < 4; ++i)
                As[kb + i][r] = (mg < Mb) ? ap[i] : 0.f;
        } else if constexpr (LD == 1) {
#pragma unroll
            for (int i = 0; i < 4; ++i) {
                const int e = tid + 256 * i;
                const int ml = e & 63, kk = e >> 6;
                const int k = k0 + kk;
                float v;
                if (k < K1) v = A[((size_t)b * K1 + k) * (size_t)Mb + m0 + ml];
                else        v = A2[((size_t)b * (K - K1) + (k - K1)) * (size_t)Mb + m0 + ml];
                As[kk][ml] = v;
            }
        } else { // LD == 2
#pragma unroll
            for (int i = 0; i < 4; ++i) {
                const int e = tid + 256 * i;
                const int ml = e & 63, kk = e >> 6;
                const int k = k0 + kk;
                const int mg = m0 + ml;
                float v = 0.f;
                if (mg < Mb) {
                    const int ci = k >> 2, ky = (k >> 1) & 1, kx = k & 1;
                    const int y = mg / 14, xx = mg - y * 14;
                    v = A[(((size_t)b * 256 + ci) * 28 + 2 * y + ky) * 28 + 2 * xx + kx];
                }
                As[kk][ml] = v;
            }
        }
        // ---- stage B tile -> Bs[k][n]  (W is (N,K) row-major)
        if constexpr (BN == 128) {
            const int n = tid >> 1, kb = (tid & 1) * 8;
            const float* wp = W + (size_t)(n0 + n) * K + k0 + kb;
#pragma unroll
            for (int i = 0; i < 8; ++i) Bs[kb + i][n] = wp[i];
        } else {
            const int n = tid >> 2, kb = (tid & 3) * 4;
            const float* wp = W + (size_t)(n0 + n) * K + k0 + kb;
#pragma unroll
            for (int i = 0; i < 4; ++i) Bs[kb + i][n] = wp[i];
        }
        __syncthreads();
#pragma unroll
        for (int kk = 0; kk < BK; ++kk) {
            float av[TM], bv[TN];
#pragma unroll
            for (int i = 0; i < TM; ++i) av[i] = As[kk][ty * TM + i];
#pragma unroll
            for (int j = 0; j < TN; ++j) bv[j] = Bs[kk][tx * TN + j];
#pragma unroll
            for (int i = 0; i < TM; ++i)
#pragma unroll
                for (int j = 0; j < TN; ++j) acc[i][j] += av[i] * bv[j];
        }
        __syncthreads();
    }

    // ---- epilogue
#pragma unroll
    for (int i = 0; i < TM; ++i) {
        const int mg = m0 + ty * TM + i;
        if (mg >= Mb) continue;
#pragma unroll
        for (int j = 0; j < TN; ++j) {
            const int c = n0 + tx * TN + j;
            const float v = acc[i][j];
            if constexpr (EPI == 0) {
                out[((size_t)b * Mb + mg) * N + c] = v + bias[c];
            } else if constexpr (EPI == 1) {
                out[((size_t)b * N + c) * (size_t)Mb + mg] = (v + bias[c]) * scale;
            } else if constexpr (EPI == 2) {
                const float inv = g[c] * rsqrtf(vv[c] + 1e-5f);
                const float r = v * inv + (bb[c] - mm[c] * inv);
                out[((size_t)b * N + c) * (size_t)Mb + mg] = r > 0.f ? r : 0.f;
            } else {
                const float val = v + bias[c];
                const int h = (c >> 5) & 7, d = c & 31;
                float* p = (c < 256) ? out : out2;
                p[(((size_t)b * 8 + h) * 196 + mg) * 32 + d] = val;
            }
        }
    }
}

// ============================== Haar DWT ===================================
// reduced (B,64,56,56) -> coeffs (B,256,28,28), channel order [ll,lh,hl,hh]
__global__ __launch_bounds__(256) void dwt_k(const float* __restrict__ in,
                                             float* __restrict__ outp)
{
    const int idx = blockIdx.x * 256 + threadIdx.x;   // 16*64*28*28 = 802816
    const int x = idx % 28;
    const int y = (idx / 28) % 28;
    const int c = (idx / 784) % 64;
    const int b = idx / (784 * 64);
    const float* ip = in + ((size_t)(b * 64 + c) * 56 + 2 * y) * 56 + 2 * x;
    const float a = ip[0], bb = ip[1], cc = ip[56], dd = ip[57];
    float* op = outp + (size_t)b * 256 * 784 + (size_t)c * 784 + y * 28 + x;
    op[0]          = (a + bb + cc + dd) * 0.5f;
    op[64 * 784]   = (a - bb + cc - dd) * 0.5f;
    op[128 * 784]  = (a + bb - cc - dd) * 0.5f;
    op[192 * 784]  = (a - bb - cc + dd) * 0.5f;
}

// ============================== Haar IDWT ==================================
// coeffs2 (B,256,28,28) -> local (B,64,56,56) channel-major
__global__ __launch_bounds__(256) void idwt_k(const float* __restrict__ in,
                                              float* __restrict__ outp)
{
    const int idx = blockIdx.x * 256 + threadIdx.x;   // 802816
    const int x = idx % 28;
    const int y = (idx / 28) % 28;
    const int c = (idx / 784) % 64;
    const int b = idx / (784 * 64);
    const float* ip = in + (size_t)b * 256 * 784 + (size_t)c * 784 + y * 28 + x;
    const float ll = ip[0], lh = ip[64 * 784], hl = ip[128 * 784], hh = ip[192 * 784];
    const float a  = (ll + lh + hl + hh) * 0.5f;
    const float b_ = (ll - lh + hl - hh) * 0.5f;
    const float c_ = (ll + lh - hl - hh) * 0.5f;
    const float d_ = (ll - lh - hl + hh) * 0.5f;
    float* op = outp + ((size_t)(b * 64 + c) * 56 + 2 * y) * 56 + 2 * x;
    op[0] = a; op[1] = b_; op[56] = c_; op[57] = d_;
}

// ============================== conv3x3 + BN + ReLU ========================
// coeffs (B,256,28,28) -> coeffs2 (B,256,28,28), pad=1
// block 256 thr: 8 co-groups x 32 lanes; lane owns 7-px strip; 32 co, 8 rows.
__global__ __launch_bounds__(256) void conv3_k(
    const float* __restrict__ in, const float* __restrict__ filt,
    const float* __restrict__ g, const float* __restrict__ bb,
    const float* __restrict__ mm, const float* __restrict__ vv,
    float* __restrict__ outp)
{
    __shared__ float s_in[8][10][30];   // ci, y0-1..y0+8, x -1..28
    __shared__ float s_w[32][8][9];
    const int tid = threadIdx.x;
    const int lane = tid & 31, cog = tid >> 5;
    const int row = lane >> 2, colstart = 7 * (lane & 3);
    const int co0 = blockIdx.x * 32;
    const int y0 = blockIdx.y * 8;
    const int b = blockIdx.z;

    float acc[4][7];
#pragma unroll
    for (int i = 0; i < 4; ++i)
#pragma unroll
        for (int p = 0; p < 7; ++p) acc[i][p] = 0.f;

    for (int cc = 0; cc < 256; cc += 8) {
        // stage input 8x10x30 = 2400
#pragma unroll
        for (int i = 0; i < 10; ++i) {
            const int e = tid + 256 * i;
            if (e < 2400) {
                const int ci = e / 300;
                const int r = (e % 300) / 30;
                const int c30 = e % 30;
                const int y = y0 + r - 1, xx = c30 - 1;
                float v = 0.f;
                if (y >= 0 && y < 28 && xx >= 0 && xx < 28)
                    v = in[(((size_t)b * 256 + cc + ci) * 28 + y) * 28 + xx];
                s_in[ci][r][c30] = v;
            }
        }
        // stage weights 32*8*9 = 2304
#pragma unroll
        for (int i = 0; i < 9; ++i) {
            const int e = tid + 256 * i;
            const int co_l = e / 72;
            const int r = e % 72;
            const int ci = r / 9, tap = r % 9;
            s_w[co_l][ci][tap] =
                filt[(size_t)(co0 + co_l) * 2304 + (size_t)(cc + ci) * 9 + tap];
        }
        __syncthreads();
#pragma unroll
        for (int ci = 0; ci < 8; ++ci) {
#pragma unroll
            for (int ky = 0; ky < 3; ++ky) {
                float inr[9];
                const float* sp = &s_in[ci][row + ky][colstart];
#pragma unroll
                for (int t = 0; t < 9; ++t) inr[t] = sp[t];
#pragma unroll
                for (int co = 0; co < 4; ++co) {
                    const float w0 = s_w[cog * 4 + co][ci][ky * 3 + 0];
                    const float w1 = s_w[cog * 4 + co][ci][ky * 3 + 1];
                    const float w2 = s_w[cog * 4 + co][ci][ky * 3 + 2];
#pragma unroll
                    for (int p = 0; p < 7; ++p)
                        acc[co][p] += w0 * inr[p] + w1 * inr[p + 1] + w2 * inr[p + 2];
                }
            }
        }
        __syncthreads();
    }
    const int y = y0 + row;
    if (y < 28) {
#pragma unroll
        for (int co = 0; co < 4; ++co) {
            const int cg = co0 + cog * 4 + co;
            const float inv = g[cg] * rsqrtf(vv[cg] + 1e-5f);
            const float beta = bb[cg] - mm[cg] * inv;
            float* op = outp + (((size_t)b * 256 + cg) * 28 + y) * 28 + colstart;
#pragma unroll
            for (int p = 0; p < 7; ++p) {
                const float r = acc[co][p] * inv + beta;
                op[p] = r > 0.f ? r : 0.f;
            }
        }
    }
}

// ============================== LayerNorm ==================================
// rows = B*196, width 256. one row per block of 256 threads.
__global__ __launch_bounds__(256) void ln_k(const float* __restrict__ in,
                                            const float* __restrict__ g,
                                            const float* __restrict__ bb,
                                            float* __restrict__ outp)
{
    const int row = blockIdx.x;
    const int t = threadIdx.x;
    const float x = in[(size_t)row * 256 + t];
    __shared__ float r1[4], r2[4];
    float s = x;
#pragma unroll
    for (int o = 32; o > 0; o >>= 1) s += __shfl_down(s, o);
    if ((t & 63) == 0) r1[t >> 6] = s;
    __syncthreads();
    const float mu = (r1[0] + r1[1] + r1[2] + r1[3]) * (1.f / 256.f);
    const float d = x - mu;
    float s2 = d * d;
#pragma unroll
    for (int o = 32; o > 0; o >>= 1) s2 += __shfl_down(s2, o);
    if ((t & 63) == 0) r2[t >> 6] = s2;
    __syncthreads();
    const float var = (r2[0] + r2[1] + r2[2] + r2[3]) * (1.f / 256.f);
    outp[(size_t)row * 256 + t] = d * rsqrtf(var + 1e-5f) * g[t] + bb[t];
}

// ============================== fused attention ============================
// q_t (B,256,3136) pre-scaled; K,V (B,8,196,32); out att_t (B,256,3136).
// grid (7, B*8), block 448; one thread per query, online softmax over 196.
__global__ __launch_bounds__(448) void attn_k(const float* __restrict__ qt,
                                              const float* __restrict__ kb,
                                              const float* __restrict__ vb,
                                              float* __restrict__ att)
{
    __shared__ float Ks[6272];
    __shared__ float Vs[6272];
    const int bh = blockIdx.y;
    const int n = blockIdx.x * 448 + threadIdx.x;
    const float* kp = kb + (size_t)bh * 6272;
    const float* vp = vb + (size_t)bh * 6272;
    for (int i = threadIdx.x; i < 6272; i += 448) {
        Ks[i] = kp[i];
        Vs[i] = vp[i];
    }
    __syncthreads();
    float q[HD];
    const float* qp = qt + (size_t)bh * HD * NSP + n;
#pragma unroll
    for (int d = 0; d < HD; ++d) q[d] = qp[(size_t)d * NSP];

    float m = -1e30f, l = 0.f;
    float acc[HD];
#pragma unroll
    for (int d = 0; d < HD; ++d) acc[d] = 0.f;

    for (int j = 0; j < KVL; ++j) {
        const float* kr = &Ks[j * 32];
        float s0 = 0.f, s1 = 0.f, s2 = 0.f, s3 = 0.f;
#pragma unroll
        for (int d = 0; d < 32; d += 4) {
            s0 += q[d] * kr[d];
            s1 += q[d + 1] * kr[d + 1];
            s2 += q[d + 2] * kr[d + 2];
            s3 += q[d + 3] * kr[d + 3];
        }
        const float s = (s0 + s1) + (s2 + s3);
        if (s > m) {
            const float corr = __expf(m - s);   // m=-inf first iter -> 0
#pragma unroll
            for (int d = 0; d < HD; ++d) acc[d] *= corr;
            l *= corr;
            m = s;
        }
        const float p = __expf(s - m);
        l += p;
        const float* vr = &Vs[j * 32];
#pragma unroll
        for (int d = 0; d < HD; ++d) acc[d] += p * vr[d];
    }
    const float rl = 1.f / l;
    float* op = att + (size_t)bh * HD * NSP + n;
#pragma unroll
    for (int d = 0; d < HD; ++d) op[(size_t)d * NSP] = acc[d] * rl;
}

// ============================== launcher ===================================
extern "C" void kernel_launch(void* const* d_in, const int* in_sizes, int n_in,
                              void* d_out, int out_size, void* d_ws, size_t ws_size,
                              hipStream_t stream)
{
    const float* x        = (const float*)d_in[0];
    const float* reduce_w = (const float*)d_in[3];
    const float* bn1_g    = (const float*)d_in[4];
    const float* bn1_b    = (const float*)d_in[5];
    const float* bn1_m    = (const float*)d_in[6];
    const float* bn1_v    = (const float*)d_in[7];
    const float* filt_w   = (const float*)d_in[8];
    const float* bn2_g    = (const float*)d_in[9];
    const float* bn2_b    = (const float*)d_in[10];
    const float* bn2_m    = (const float*)d_in[11];
    const float* bn2_v    = (const float*)d_in[12];
    const float* kve_w    = (const float*)d_in[13];
    const float* kve_b    = (const float*)d_in[14];
    const float* q_w      = (const float*)d_in[15];
    const float* q_b      = (const float*)d_in[16];
    const float* kvn_g    = (const float*)d_in[17];
    const float* kvn_b    = (const float*)d_in[18];
    const float* kv_w     = (const float*)d_in[19];
    const float* kv_b     = (const float*)d_in[20];
    const float* proj_w   = (const float*)d_in[21];
    const float* proj_b   = (const float*)d_in[22];

    float* out = (float*)d_out;
    float* ws  = (float*)d_ws;

    float* att_t  = ws;                       // 12,845,056  (B,256,3136)
    float* bufC   = att_t + 12845056;         //  3,211,264  reduced / coeffs2
    float* bufD   = bufC + 3211264;           //  3,211,264  coeffs / local
    float* kv_src = bufD + 3211264;           //    802,816  (B,196,256)
    float* kv_ln  = kv_src + 802816;          //    802,816
    float* kbuf   = kv_ln + 802816;           //    802,816  (B,8,196,32)
    float* vbuf   = kbuf + 802816;            //    802,816
    // q_t lives in d_out until attention consumes it; proj overwrites d_out.

    const float scale = 0.17677669529663689f; // 1/sqrt(32)

    // 1. q = (x @ q_w^T + q_b) * scale  -> q_t (B,256,3136) in d_out
    gemm_k<128, 8, 0, 1><<<dim3(49, 2, B_), 256, 0, stream>>>(
        x, nullptr, q_w, q_b, nullptr, nullptr, nullptr, nullptr,
        out, nullptr, NSP, 256, 256, 0, scale);

    // 2. reduced = relu(bn1(conv1x1(x))) -> (B,64,3136)
    gemm_k<64, 4, 0, 2><<<dim3(49, 1, B_), 256, 0, stream>>>(
        x, nullptr, reduce_w, nullptr, bn1_g, bn1_b, bn1_m, bn1_v,
        bufC, nullptr, NSP, 64, 256, 0, 0.f);

    // 3. coeffs = dwt(reduced) -> (B,256,784) in bufD
    dwt_k<<<3136, 256, 0, stream>>>(bufC, bufD);

    // 4. coeffs2 = relu(bn2(conv3x3(coeffs))) -> bufC
    conv3_k<<<dim3(8, 4, B_), 256, 0, stream>>>(
        bufD, filt_w, bn2_g, bn2_b, bn2_m, bn2_v, bufC);

    // 5. local = idwt(coeffs2) -> (B,64,3136) in bufD
    idwt_k<<<3136, 256, 0, stream>>>(bufC, bufD);

    // 6. kv_src = conv2x2s2(coeffs2) + kve_b -> (B,196,256), implicit im2col
    gemm_k<128, 8, 2, 0><<<dim3(4, 2, B_), 256, 0, stream>>>(
        bufC, nullptr, kve_w, kve_b, nullptr, nullptr, nullptr, nullptr,
        kv_src, nullptr, KVL, 256, 1024, 0, 0.f);

    // 7. layernorm
    ln_k<<<B_ * KVL, 256, 0, stream>>>(kv_src, kvn_g, kvn_b, kv_ln);

    // 8. kv = kv_ln @ kv_w^T + kv_b -> K,V (B,8,196,32)
    gemm_k<128, 8, 0, 3><<<dim3(4, 4, B_), 256, 0, stream>>>(
        kv_ln, nullptr, kv_w, kv_b, nullptr, nullptr, nullptr, nullptr,
        kbuf, vbuf, KVL, 512, 256, 0, 0.f);

    // 9. attention -> att_t (B,256,3136)
    attn_k<<<dim3(7, B_ * HEADS), 448, 0, stream>>>(out, kbuf, vbuf, att_t);

    // 10. out = concat(att, local) @ proj_w^T + proj_b -> (B,3136,256)
    gemm_k<128, 8, 1, 0><<<dim3(49, 2, B_), 256, 0, stream>>>(
        att_t, bufD, proj_w, proj_b, nullptr, nullptr, nullptr, nullptr,
        out, nullptr, NSP, 256, 320, 256, 0.f);
}

// Round 2
// 745.269 us; speedup vs baseline: 1.7913x; 1.7913x over previous
//
#include <hip/hip_runtime.h>
#include <math.h>

// ---------------------------------------------------------------------------
// WaveViT attention block. bf16 MFMA for all GEMM-shaped ops, f32 attention.
// B=16, Nsp=3136 (56x56), C=256, heads=8, hd=32, red=64, sr=2
// ---------------------------------------------------------------------------

#define B_   16
#define NSP  3136
#define KVL  196
#define HD   32

typedef short bf16x8 __attribute__((ext_vector_type(8)));
typedef float f32x4  __attribute__((ext_vector_type(4)));

__device__ inline unsigned int f2bf(float f) {
    unsigned int u = __float_as_uint(f);
    u += 0x7FFFu + ((u >> 16) & 1u);
    return u >> 16;   // round-to-nearest-even bf16 bits in low 16
}

// ========================= weight conversions ==============================
// fused plain f32->bf16 for q_w(65536), reduce_w(16384), kve_w(262144),
// kv_w(131072), proj_w(81920). 4 elems/thread. 544 blocks x 256.
__global__ __launch_bounds__(256) void wcvt_k(
    const float* __restrict__ q, const float* __restrict__ red,
    const float* __restrict__ kve, const float* __restrict__ kv,
    const float* __restrict__ proj, unsigned short* __restrict__ dst)
{
    const int i = blockIdx.x * 256 + threadIdx.x;
    const int e = i * 4;
    const float* src; int off;
    if (e < 65536)       { src = q;    off = e; }
    else if (e < 81920)  { src = red;  off = e - 65536; }
    else if (e < 344064) { src = kve;  off = e - 81920; }
    else if (e < 475136) { src = kv;   off = e - 344064; }
    else                 { src = proj; off = e - 475136; }
    const float4 v = *(const float4*)(src + off);
    const unsigned int p0 = f2bf(v.x) | (f2bf(v.y) << 16);
    const unsigned int p1 = f2bf(v.z) | (f2bf(v.w) << 16);
    *(uint2*)(dst + e) = make_uint2(p0, p1);
}

// filt_w (256,256,3,3) -> bf16 [n][k'] with k' = tap*256 + ci  (tap-major)
__global__ __launch_bounds__(256) void wcvt3_k(const float* __restrict__ filt,
                                               unsigned short* __restrict__ wf)
{
    const int i = blockIdx.x * 256 + threadIdx.x;   // 147456 = 576*256
    const int n = i / 576;
    const int rem = (i - n * 576) * 4;
    const int tap = rem >> 8;
    const int ci = rem & 255;
    const float* s = filt + (size_t)n * 2304;       // [ci][tap] taps=9
    const unsigned int t0 = f2bf(s[(ci + 0) * 9 + tap]);
    const unsigned int t1 = f2bf(s[(ci + 1) * 9 + tap]);
    const unsigned int t2 = f2bf(s[(ci + 2) * 9 + tap]);
    const unsigned int t3 = f2bf(s[(ci + 3) * 9 + tap]);
    *(uint2*)(wf + (size_t)n * 2304 + rem) = make_uint2(t0 | (t1 << 16), t2 | (t3 << 16));
}

// x (B,3136,256) f32 -> x_bf (B,3200,256) bf16, zero pad rows
__global__ __launch_bounds__(256) void cvtx_k(const float* __restrict__ x,
                                              unsigned short* __restrict__ xb)
{
    const int i = blockIdx.x * 256 + threadIdx.x;   // 3,276,800
    const int c4 = (i & 63) * 4;
    const int row = (i >> 6) % 3200;
    const int b = (i >> 6) / 3200;
    unsigned int p0 = 0, p1 = 0;
    if (row < 3136) {
        const float4 v = *(const float4*)(x + ((size_t)(b * 3136 + row)) * 256 + c4);
        p0 = f2bf(v.x) | (f2bf(v.y) << 16);
        p1 = f2bf(v.z) | (f2bf(v.w) << 16);
    }
    *(uint2*)(xb + ((size_t)(b * 3200) + row) * 256 + c4) = make_uint2(p0, p1);
}

// ============================ MFMA GEMM ====================================
// C[m,n] = sum_k A[m,k]*W[n,k]. BM=128, BK=32, 4 waves (2x2), 16x16x32 bf16.
// LDM 0: A = bf16 [B][Mpad][K] row-major.
// LDM 1: implicit im2col 3x3 pad1 on f32 Af (B,256,28,28), K order tap*256+ci.
// EPI 0: out[(b*Mv+m)*N+n] = v + bias[n]                      (row-major)
// EPI 1: out[(b*N+n)*Mv+m] = (v+bias[n])*scale                (transposed)
// EPI 2: out[(b*N+n)*Mv+m] = relu(BN(v))                      (transposed)
// EPI 3: kv split -> out/out2 ((b*8+h)*196+m)*32+d
template<int BN, int EPI, int LDM>
__global__ __launch_bounds__(256) void mgemm(
    const unsigned short* __restrict__ A, const float* __restrict__ Af,
    const unsigned short* __restrict__ W, const float* __restrict__ bias,
    const float* __restrict__ g, const float* __restrict__ bb,
    const float* __restrict__ mm, const float* __restrict__ vv,
    float* __restrict__ out, float* __restrict__ out2,
    int Mpad, int Mvalid, int N, int K, float scale)
{
    constexpr int FN = BN / 32;       // frags per wave in n: 128->4, 64->2
    __shared__ short As[128][32];
    __shared__ short Bs[BN][32];
    const int tid = threadIdx.x, lane = tid & 63;
    const int w = tid >> 6, wr = w >> 1, wc = w & 1;
    const int b = blockIdx.z, m0 = blockIdx.x * 128, n0 = blockIdx.y * BN;
    const unsigned short* Ab = A + ((size_t)b * Mpad + m0) * (size_t)K;
    const unsigned short* Wb = W + (size_t)n0 * K;

    // per-round staging row geometry (constant across K loop)
    const int r_row0 = tid >> 2, r_c16 = tid & 3;
    int ym[2], xm[2], mm_[2];
#pragma unroll
    for (int rnd = 0; rnd < 2; ++rnd) {
        const int m = m0 + rnd * 64 + r_row0;
        mm_[rnd] = m;
        ym[rnd] = m / 28;
        xm[rnd] = m - 28 * ym[rnd];
    }

    f32x4 acc[4][FN];
#pragma unroll
    for (int i = 0; i < 4; ++i)
#pragma unroll
        for (int j = 0; j < FN; ++j) acc[i][j] = (f32x4){0.f, 0.f, 0.f, 0.f};

    for (int k0 = 0; k0 < K; k0 += 32) {
        // ---- stage A (2 rounds of 16B/thread)
#pragma unroll
        for (int rnd = 0; rnd < 2; ++rnd) {
            const int row = rnd * 64 + r_row0;
            if constexpr (LDM == 0) {
                *(int4*)&As[row][r_c16 * 8] =
                    *(const int4*)(Ab + (size_t)row * K + k0 + r_c16 * 8);
            } else {
                const int kk = k0 + r_c16 * 8;
                const int tap = kk >> 8;
                const int ci0 = kk & 255;
                const int ky = tap / 3, kx = tap - 3 * ky;
                const int sy = ym[rnd] + ky - 1, sx = xm[rnd] + kx - 1;
                unsigned int p0 = 0, p1 = 0, p2 = 0, p3 = 0;
                if (mm_[rnd] < Mvalid && sy >= 0 && sy < 28 && sx >= 0 && sx < 28) {
                    const float* sp = Af + ((size_t)b * 256 + ci0) * 784 + sy * 28 + sx;
                    p0 = f2bf(sp[0])        | (f2bf(sp[784])     << 16);
                    p1 = f2bf(sp[2 * 784])  | (f2bf(sp[3 * 784]) << 16);
                    p2 = f2bf(sp[4 * 784])  | (f2bf(sp[5 * 784]) << 16);
                    p3 = f2bf(sp[6 * 784])  | (f2bf(sp[7 * 784]) << 16);
                }
                *(int4*)&As[row][r_c16 * 8] = make_int4(p0, p1, p2, p3);
            }
        }
        // ---- stage B
#pragma unroll
        for (int rnd = 0; rnd < BN / 64; ++rnd) {
            const int row = rnd * 64 + r_row0;
            *(int4*)&Bs[row][r_c16 * 8] =
                *(const int4*)(Wb + (size_t)row * K + k0 + r_c16 * 8);
        }
        __syncthreads();
        bf16x8 af[4], bfr[FN];
#pragma unroll
        for (int i = 0; i < 4; ++i)
            af[i] = *(const bf16x8*)&As[wr * 64 + i * 16 + (lane & 15)][(lane >> 4) * 8];
#pragma unroll
        for (int j = 0; j < FN; ++j)
            bfr[j] = *(const bf16x8*)&Bs[wc * (FN * 16) + j * 16 + (lane & 15)][(lane >> 4) * 8];
#pragma unroll
        for (int i = 0; i < 4; ++i)
#pragma unroll
            for (int j = 0; j < FN; ++j)
                acc[i][j] = __builtin_amdgcn_mfma_f32_16x16x32_bf16(af[i], bfr[j], acc[i][j], 0, 0, 0);
        __syncthreads();
    }

    // ---- epilogue.  C/D: col=lane&15, row=(lane>>4)*4+reg
    const int cl = lane & 15, rh = lane >> 4;
#pragma unroll
    for (int i = 0; i < 4; ++i) {
#pragma unroll
        for (int j = 0; j < FN; ++j) {
            const int n = n0 + wc * (FN * 16) + j * 16 + cl;
#pragma unroll
            for (int r = 0; r < 4; ++r) {
                const int m = m0 + wr * 64 + i * 16 + rh * 4 + r;
                if (m >= Mvalid) continue;
                const float v = acc[i][j][r];
                if constexpr (EPI == 0) {
                    out[((size_t)b * Mvalid + m) * N + n] = v + bias[n];
                } else if constexpr (EPI == 1) {
                    out[((size_t)b * N + n) * (size_t)Mvalid + m] = (v + bias[n]) * scale;
                } else if constexpr (EPI == 2) {
                    const float inv = g[n] * rsqrtf(vv[n] + 1e-5f);
                    const float rr = v * inv + (bb[n] - mm[n] * inv);
                    out[((size_t)b * N + n) * (size_t)Mvalid + m] = rr > 0.f ? rr : 0.f;
                } else {
                    const float val = v + bias[n];
                    const int h = (n >> 5) & 7, d = n & 31;
                    float* p2 = (n < 256) ? out : out2;
                    p2[(((size_t)b * 8 + h) * 196 + m) * 32 + d] = val;
                }
            }
        }
    }
}

// ============================== Haar DWT ===================================
__global__ __launch_bounds__(256) void dwt_k(const float* __restrict__ in,
                                             float* __restrict__ outp)
{
    const int idx = blockIdx.x * 256 + threadIdx.x;   // 802816
    const int x = idx % 28;
    const int y = (idx / 28) % 28;
    const int c = (idx / 784) % 64;
    const int b = idx / (784 * 64);
    const float* ip = in + (size_t)(b * 64 + c) * 3136 + (2 * y) * 56 + 2 * x;
    const float a = ip[0], bb = ip[1], cc = ip[56], dd = ip[57];
    float* op = outp + (size_t)b * 200704 + (size_t)c * 784 + y * 28 + x;
    op[0]         = (a + bb + cc + dd) * 0.5f;
    op[64 * 784]  = (a - bb + cc - dd) * 0.5f;
    op[128 * 784] = (a + bb - cc - dd) * 0.5f;
    op[192 * 784] = (a - bb - cc + dd) * 0.5f;
}

// ============================== Haar IDWT -> aproj cols 256..319 ===========
__global__ __launch_bounds__(256) void idwt_k(const float* __restrict__ in,
                                              unsigned short* __restrict__ aproj)
{
    const int idx = blockIdx.x * 256 + threadIdx.x;   // 802816
    const int x = idx % 28;
    const int y = (idx / 28) % 28;
    const int c = (idx / 784) % 64;
    const int b = idx / (784 * 64);
    const float* ip = in + (size_t)b * 200704 + (size_t)c * 784 + y * 28 + x;
    const float ll = ip[0], lh = ip[64 * 784], hl = ip[128 * 784], hh = ip[192 * 784];
    const float a  = (ll + lh + hl + hh) * 0.5f;
    const float b_ = (ll - lh + hl - hh) * 0.5f;
    const float c_ = (ll + lh - hl - hh) * 0.5f;
    const float d_ = (ll - lh - hl + hh) * 0.5f;
    const int m = (2 * y) * 56 + 2 * x;
    unsigned short* op = aproj + ((size_t)b * 3200 + m) * 320 + 256 + c;
    op[0]            = (unsigned short)f2bf(a);
    op[320]          = (unsigned short)f2bf(b_);
    op[320 * 56]     = (unsigned short)f2bf(c_);
    op[320 * 56+320] = (unsigned short)f2bf(d_);
}

// ============================== kve im2col (2x2 s2) -> bf16 ================
__global__ __launch_bounds__(256) void im2col_kve_k(const float* __restrict__ c2,
                                                    unsigned short* __restrict__ dst)
{
    const int i = blockIdx.x * 256 + threadIdx.x;   // 1,048,576
    const int ci = i & 255;
    const int m = (i >> 8) & 255;
    const int b = i >> 16;
    unsigned int p0 = 0, p1 = 0;
    if (m < 196) {
        const int y = m / 14, x = m - 14 * y;
        const float* sp = c2 + ((size_t)(b * 256 + ci)) * 784 + (2 * y) * 28 + 2 * x;
        p0 = f2bf(sp[0])  | (f2bf(sp[1])  << 16);
        p1 = f2bf(sp[28]) | (f2bf(sp[29]) << 16);
    }
    *(uint2*)(dst + ((size_t)(b * 256 + m)) * 1024 + ci * 4) = make_uint2(p0, p1);
}

// ============================== LayerNorm -> bf16, pad rows ================
__global__ __launch_bounds__(256) void ln_k(const float* __restrict__ in,
                                            const float* __restrict__ g,
                                            const float* __restrict__ bb,
                                            unsigned short* __restrict__ outp)
{
    const int rg = blockIdx.x;            // 0..4095
    const int rl = rg & 255, b = rg >> 8;
    const int t = threadIdx.x;
    unsigned short* op = outp + (size_t)rg * 256 + t;
    if (rl >= 196) { *op = 0; return; }
    const float x = in[((size_t)(b * 196) + rl) * 256 + t];
    __shared__ float r1[4], r2[4];
    float s = x;
#pragma unroll
    for (int o = 32; o > 0; o >>= 1) s += __shfl_down(s, o);
    if ((t & 63) == 0) r1[t >> 6] = s;
    __syncthreads();
    const float mu = (r1[0] + r1[1] + r1[2] + r1[3]) * (1.f / 256.f);
    const float d = x - mu;
    float s2 = d * d;
#pragma unroll
    for (int o = 32; o > 0; o >>= 1) s2 += __shfl_down(s2, o);
    if ((t & 63) == 0) r2[t >> 6] = s2;
    __syncthreads();
    const float var = (r2[0] + r2[1] + r2[2] + r2[3]) * (1.f / 256.f);
    *op = (unsigned short)f2bf(d * rsqrtf(var + 1e-5f) * g[t] + bb[t]);
}

// ============================== fused attention (f32) ======================
// q_t (B,256,3136) pre-scaled in d_out; K,V (B,8,196,32) f32;
// writes attended rows as bf16 into aproj cols 0..255.
__global__ __launch_bounds__(448) void attn_k(const float* __restrict__ qt,
                                              const float* __restrict__ kb,
                                              const float* __restrict__ vb,
                                              unsigned short* __restrict__ aproj)
{
    __shared__ float Ks[6272];
    __shared__ float Vs[6272];
    const int bh = blockIdx.y;
    const int b = bh >> 3, h = bh & 7;
    const int n = blockIdx.x * 448 + threadIdx.x;
    const float* kp = kb + (size_t)bh * 6272;
    const float* vp = vb + (size_t)bh * 6272;
    for (int i = threadIdx.x; i < 6272; i += 448) {
        Ks[i] = kp[i];
        Vs[i] = vp[i];
    }
    __syncthreads();
    float q[HD];
    const float* qp = qt + (size_t)bh * HD * NSP + n;
#pragma unroll
    for (int d = 0; d < HD; ++d) q[d] = qp[(size_t)d * NSP];

    float m = -1e30f, l = 0.f;
    float acc[HD];
#pragma unroll
    for (int d = 0; d < HD; ++d) acc[d] = 0.f;

    for (int j = 0; j < KVL; ++j) {
        const float* kr = &Ks[j * 32];
        float s0 = 0.f, s1 = 0.f, s2 = 0.f, s3 = 0.f;
#pragma unroll
        for (int d = 0; d < 32; d += 4) {
            s0 += q[d] * kr[d];
            s1 += q[d + 1] * kr[d + 1];
            s2 += q[d + 2] * kr[d + 2];
            s3 += q[d + 3] * kr[d + 3];
        }
        const float s = (s0 + s1) + (s2 + s3);
        if (s > m) {
            const float corr = __expf(m - s);
#pragma unroll
            for (int d = 0; d < HD; ++d) acc[d] *= corr;
            l *= corr;
            m = s;
        }
        const float p = __expf(s - m);
        l += p;
        const float* vr = &Vs[j * 32];
#pragma unroll
        for (int d = 0; d < HD; ++d) acc[d] += p * vr[d];
    }
    const float rl = 1.f / l;
    unsigned short* op = aproj + ((size_t)b * 3200 + n) * 320 + h * 32;
    unsigned int p[16];
#pragma unroll
    for (int d = 0; d < 16; ++d)
        p[d] = f2bf(acc[2 * d] * rl) | (f2bf(acc[2 * d + 1] * rl) << 16);
#pragma unroll
    for (int d = 0; d < 4; ++d)
        ((uint4*)op)[d] = make_uint4(p[4 * d], p[4 * d + 1], p[4 * d + 2], p[4 * d + 3]);
}

// ============================== launcher ===================================
extern "C" void kernel_launch(void* const* d_in, const int* in_sizes, int n_in,
                              void* d_out, int out_size, void* d_ws, size_t ws_size,
                              hipStream_t stream)
{
    const float* x        = (const float*)d_in[0];
    const float* reduce_w = (const float*)d_in[3];
    const float* bn1_g    = (const float*)d_in[4];
    const float* bn1_b    = (const float*)d_in[5];
    const float* bn1_m    = (const float*)d_in[6];
    const float* bn1_v    = (const float*)d_in[7];
    const float* filt_w   = (const float*)d_in[8];
    const float* bn2_g    = (const float*)d_in[9];
    const float* bn2_b    = (const float*)d_in[10];
    const float* bn2_m    = (const float*)d_in[11];
    const float* bn2_v    = (const float*)d_in[12];
    const float* kve_w    = (const float*)d_in[13];
    const float* kve_b    = (const float*)d_in[14];
    const float* q_w      = (const float*)d_in[15];
    const float* q_b      = (const float*)d_in[16];
    const float* kvn_g    = (const float*)d_in[17];
    const float* kvn_b    = (const float*)d_in[18];
    const float* kv_w     = (const float*)d_in[19];
    const float* kv_b     = (const float*)d_in[20];
    const float* proj_w   = (const float*)d_in[21];
    const float* proj_b   = (const float*)d_in[22];

    float* out = (float*)d_out;
    float* ws  = (float*)d_ws;

    // ws layout (floats). aproj overlaps x_bf in time (x_bf dead before idwt).
    unsigned short* aproj  = (unsigned short*)ws;            // 16,384,000 us
    unsigned short* x_bf   = (unsigned short*)ws;            // 13,107,200 us (dies first)
    unsigned short* a_kve  = (unsigned short*)(ws + 8192000);  // 4,194,304 us
    float* bufC   = ws + 10289152;   // 3,211,264 f  (reduced / coeffs2)
    float* bufD   = ws + 13500416;   // 3,211,264 f  (coeffs)
    float* kv_src = ws + 16711680;   //   802,816 f
    float* kbuf   = ws + 17514496;   //   802,816 f
    float* vbuf   = ws + 18317312;   //   802,816 f
    unsigned short* kv_ln = (unsigned short*)(ws + 19120128); // 1,048,576 us
    unsigned short* wpl   = (unsigned short*)(ws + 19644416); //   557,056 us
    unsigned short* wfilt = (unsigned short*)(ws + 19922944); //   589,824 us
    unsigned short* wq    = wpl;
    unsigned short* wred  = wpl + 65536;
    unsigned short* wkve  = wpl + 81920;
    unsigned short* wkv   = wpl + 344064;
    unsigned short* wproj = wpl + 475136;

    const float scale = 0.17677669529663689f; // 1/sqrt(32)

    wcvt_k<<<544, 256, 0, stream>>>(q_w, reduce_w, kve_w, kv_w, proj_w, wpl);
    wcvt3_k<<<576, 256, 0, stream>>>(filt_w, wfilt);
    cvtx_k<<<12800, 256, 0, stream>>>(x, x_bf);

    // q = (x @ q_w^T + q_b)*scale -> q_t (B,256,3136) in d_out
    mgemm<128, 1, 0><<<dim3(25, 2, B_), 256, 0, stream>>>(
        x_bf, nullptr, wq, q_b, nullptr, nullptr, nullptr, nullptr,
        out, nullptr, 3200, 3136, 256, 256, scale);

    // reduced = relu(bn1(x @ reduce_w^T)) -> bufC (B,64,3136)
    mgemm<64, 2, 0><<<dim3(25, 1, B_), 256, 0, stream>>>(
        x_bf, nullptr, wred, nullptr, bn1_g, bn1_b, bn1_m, bn1_v,
        bufC, nullptr, 3200, 3136, 64, 256, 0.f);

    // coeffs = dwt(reduced) -> bufD (B,256,784)
    dwt_k<<<3136, 256, 0, stream>>>(bufC, bufD);

    // coeffs2 = relu(bn2(conv3x3(coeffs))) -> bufC, implicit im2col K=2304
    mgemm<64, 2, 1><<<dim3(7, 4, B_), 256, 0, stream>>>(
        nullptr, bufD, wfilt, nullptr, bn2_g, bn2_b, bn2_m, bn2_v,
        bufC, nullptr, 896, 784, 256, 2304, 0.f);

    // local = idwt(coeffs2) -> aproj cols 256..319 (bf16)
    idwt_k<<<3136, 256, 0, stream>>>(bufC, aproj);

    // kve im2col -> a_kve (B,256,1024) bf16
    im2col_kve_k<<<4096, 256, 0, stream>>>(bufC, a_kve);

    // kv_src = im2col @ kve_w^T + kve_b -> (B,196,256) f32
    mgemm<128, 0, 0><<<dim3(2, 2, B_), 256, 0, stream>>>(
        a_kve, nullptr, wkve, kve_b, nullptr, nullptr, nullptr, nullptr,
        kv_src, nullptr, 256, 196, 256, 1024, 0.f);

    // layernorm -> kv_ln (B,256,256) bf16, zero pad rows
    ln_k<<<4096, 256, 0, stream>>>(kv_src, kvn_g, kvn_b, kv_ln);

    // kv = kv_ln @ kv_w^T + kv_b -> K,V (B,8,196,32) f32
    mgemm<128, 3, 0><<<dim3(2, 4, B_), 256, 0, stream>>>(
        kv_ln, nullptr, wkv, kv_b, nullptr, nullptr, nullptr, nullptr,
        kbuf, vbuf, 256, 196, 512, 256, 0.f);

    // attention -> aproj cols 0..255 (bf16)
    attn_k<<<dim3(7, B_ * 8), 448, 0, stream>>>(out, kbuf, vbuf, aproj);

    // out = concat(att, local) @ proj_w^T + proj_b -> (B,3136,256) f32
    mgemm<128, 0, 0><<<dim3(25, 2, B_), 256, 0, stream>>>(
        aproj, nullptr, wproj, proj_b, nullptr, nullptr, nullptr, nullptr,
        out, nullptr, 3200, 3136, 256, 320, 0.f);
}

// Round 3
// 406.066 us; speedup vs baseline: 3.2876x; 1.8353x over previous
//
#include <hip/hip_runtime.h>
#include <hip/hip_bf16.h>
#include <math.h>

// ---------------------------------------------------------------------------
// WaveViT attention block. bf16 MFMA for all GEMM-shaped ops AND attention.
// B=16, Nsp=3136 (56x56), C=256, heads=8, hd=32, red=64, sr=2
// ---------------------------------------------------------------------------

#define B_   16
#define NSP  3136
#define KVL  196
#define HD   32

typedef short bf16x8 __attribute__((ext_vector_type(8)));
typedef float f32x4  __attribute__((ext_vector_type(4)));

__device__ inline unsigned int f2bf(float f) {
    unsigned int u = __float_as_uint(f);
    u += 0x7FFFu + ((u >> 16) & 1u);
    return u >> 16;   // round-to-nearest-even bf16 bits in low 16
}

// ========================= weight conversions ==============================
__global__ __launch_bounds__(256) void wcvt_k(
    const float* __restrict__ q, const float* __restrict__ red,
    const float* __restrict__ kve, const float* __restrict__ kv,
    const float* __restrict__ proj, unsigned short* __restrict__ dst)
{
    const int i = blockIdx.x * 256 + threadIdx.x;
    const int e = i * 4;
    const float* src; int off;
    if (e < 65536)       { src = q;    off = e; }
    else if (e < 81920)  { src = red;  off = e - 65536; }
    else if (e < 344064) { src = kve;  off = e - 81920; }
    else if (e < 475136) { src = kv;   off = e - 344064; }
    else                 { src = proj; off = e - 475136; }
    const float4 v = *(const float4*)(src + off);
    const unsigned int p0 = f2bf(v.x) | (f2bf(v.y) << 16);
    const unsigned int p1 = f2bf(v.z) | (f2bf(v.w) << 16);
    *(uint2*)(dst + e) = make_uint2(p0, p1);
}

// filt_w (256,256,3,3) -> bf16 [n][k'] with k' = tap*256 + ci  (tap-major)
__global__ __launch_bounds__(256) void wcvt3_k(const float* __restrict__ filt,
                                               unsigned short* __restrict__ wf)
{
    const int i = blockIdx.x * 256 + threadIdx.x;   // 147456 = 576*256
    const int n = i / 576;
    const int rem = (i - n * 576) * 4;
    const int tap = rem >> 8;
    const int ci = rem & 255;
    const float* s = filt + (size_t)n * 2304;
    const unsigned int t0 = f2bf(s[(ci + 0) * 9 + tap]);
    const unsigned int t1 = f2bf(s[(ci + 1) * 9 + tap]);
    const unsigned int t2 = f2bf(s[(ci + 2) * 9 + tap]);
    const unsigned int t3 = f2bf(s[(ci + 3) * 9 + tap]);
    *(uint2*)(wf + (size_t)n * 2304 + rem) = make_uint2(t0 | (t1 << 16), t2 | (t3 << 16));
}

// x (B,3136,256) f32 -> x_bf (B,3200,256) bf16, zero pad rows
__global__ __launch_bounds__(256) void cvtx_k(const float* __restrict__ x,
                                              unsigned short* __restrict__ xb)
{
    const int i = blockIdx.x * 256 + threadIdx.x;   // 3,276,800
    const int c4 = (i & 63) * 4;
    const int row = (i >> 6) % 3200;
    const int b = (i >> 6) / 3200;
    unsigned int p0 = 0, p1 = 0;
    if (row < 3136) {
        const float4 v = *(const float4*)(x + ((size_t)(b * 3136 + row)) * 256 + c4);
        p0 = f2bf(v.x) | (f2bf(v.y) << 16);
        p1 = f2bf(v.z) | (f2bf(v.w) << 16);
    }
    *(uint2*)(xb + ((size_t)(b * 3200) + row) * 256 + c4) = make_uint2(p0, p1);
}

// ============================ MFMA GEMM ====================================
// C[m,n] = sum_k A[m,k]*W[n,k]. BM=128, BK=32, 4 waves (2x2), 16x16x32 bf16.
// LDM 0: A = bf16 [B][Mpad][K] row-major.
// LDM 1: implicit im2col 3x3 pad1 on f32 Af (B,256,28,28), K order tap*256+ci.
// EPI 0: out[(b*Mv+m)*N+n] = v + bias[n]                   (f32 row-major)
// EPI 1: bf16 head-major Q: qb[((b*8+h)*3136+m)*32+d] = (v+bias)*scale
// EPI 2: out[(b*N+n)*Mv+m] = relu(BN(v))                   (f32 transposed)
// EPI 3: bf16 K (b,h,224,32) / V^T (b,h,32,224) split
template<int BN, int EPI, int LDM>
__global__ __launch_bounds__(256) void mgemm(
    const unsigned short* __restrict__ A, const float* __restrict__ Af,
    const unsigned short* __restrict__ W, const float* __restrict__ bias,
    const float* __restrict__ g, const float* __restrict__ bb,
    const float* __restrict__ mm, const float* __restrict__ vv,
    float* __restrict__ out, float* __restrict__ out2,
    int Mpad, int Mvalid, int N, int K, float scale)
{
    constexpr int FN = BN / 32;
    __shared__ short As[128][32];
    __shared__ short Bs[BN][32];
    const int tid = threadIdx.x, lane = tid & 63;
    const int w = tid >> 6, wr = w >> 1, wc = w & 1;
    const int b = blockIdx.z, m0 = blockIdx.x * 128, n0 = blockIdx.y * BN;
    const unsigned short* Ab = A + ((size_t)b * Mpad + m0) * (size_t)K;
    const unsigned short* Wb = W + (size_t)n0 * K;

    const int r_row0 = tid >> 2, r_c16 = tid & 3;
    int ym[2], xm[2], mm_[2];
#pragma unroll
    for (int rnd = 0; rnd < 2; ++rnd) {
        const int m = m0 + rnd * 64 + r_row0;
        mm_[rnd] = m;
        ym[rnd] = m / 28;
        xm[rnd] = m - 28 * ym[rnd];
    }

    f32x4 acc[4][FN];
#pragma unroll
    for (int i = 0; i < 4; ++i)
#pragma unroll
        for (int j = 0; j < FN; ++j) acc[i][j] = (f32x4){0.f, 0.f, 0.f, 0.f};

    for (int k0 = 0; k0 < K; k0 += 32) {
#pragma unroll
        for (int rnd = 0; rnd < 2; ++rnd) {
            const int row = rnd * 64 + r_row0;
            if constexpr (LDM == 0) {
                *(int4*)&As[row][r_c16 * 8] =
                    *(const int4*)(Ab + (size_t)row * K + k0 + r_c16 * 8);
            } else {
                const int kk = k0 + r_c16 * 8;
                const int tap = kk >> 8;
                const int ci0 = kk & 255;
                const int ky = tap / 3, kx = tap - 3 * ky;
                const int sy = ym[rnd] + ky - 1, sx = xm[rnd] + kx - 1;
                unsigned int p0 = 0, p1 = 0, p2 = 0, p3 = 0;
                if (mm_[rnd] < Mvalid && sy >= 0 && sy < 28 && sx >= 0 && sx < 28) {
                    const float* sp = Af + ((size_t)b * 256 + ci0) * 784 + sy * 28 + sx;
                    p0 = f2bf(sp[0])        | (f2bf(sp[784])     << 16);
                    p1 = f2bf(sp[2 * 784])  | (f2bf(sp[3 * 784]) << 16);
                    p2 = f2bf(sp[4 * 784])  | (f2bf(sp[5 * 784]) << 16);
                    p3 = f2bf(sp[6 * 784])  | (f2bf(sp[7 * 784]) << 16);
                }
                *(int4*)&As[row][r_c16 * 8] = make_int4(p0, p1, p2, p3);
            }
        }
#pragma unroll
        for (int rnd = 0; rnd < BN / 64; ++rnd) {
            const int row = rnd * 64 + r_row0;
            *(int4*)&Bs[row][r_c16 * 8] =
                *(const int4*)(Wb + (size_t)row * K + k0 + r_c16 * 8);
        }
        __syncthreads();
        bf16x8 af[4], bfr[FN];
#pragma unroll
        for (int i = 0; i < 4; ++i)
            af[i] = *(const bf16x8*)&As[wr * 64 + i * 16 + (lane & 15)][(lane >> 4) * 8];
#pragma unroll
        for (int j = 0; j < FN; ++j)
            bfr[j] = *(const bf16x8*)&Bs[wc * (FN * 16) + j * 16 + (lane & 15)][(lane >> 4) * 8];
#pragma unroll
        for (int i = 0; i < 4; ++i)
#pragma unroll
            for (int j = 0; j < FN; ++j)
                acc[i][j] = __builtin_amdgcn_mfma_f32_16x16x32_bf16(af[i], bfr[j], acc[i][j], 0, 0, 0);
        __syncthreads();
    }

    const int cl = lane & 15, rh = lane >> 4;
#pragma unroll
    for (int i = 0; i < 4; ++i) {
#pragma unroll
        for (int j = 0; j < FN; ++j) {
            const int n = n0 + wc * (FN * 16) + j * 16 + cl;
#pragma unroll
            for (int r = 0; r < 4; ++r) {
                const int m = m0 + wr * 64 + i * 16 + rh * 4 + r;
                if (m >= Mvalid) continue;
                const float v = acc[i][j][r];
                if constexpr (EPI == 0) {
                    out[((size_t)b * Mvalid + m) * N + n] = v + bias[n];
                } else if constexpr (EPI == 1) {
                    unsigned short* qp = (unsigned short*)out;
                    const int h = (n >> 5) & 7, d = n & 31;
                    qp[(((size_t)b * 8 + h) * 3136 + m) * 32 + d] =
                        (unsigned short)f2bf((v + bias[n]) * scale);
                } else if constexpr (EPI == 2) {
                    const float inv = g[n] * rsqrtf(vv[n] + 1e-5f);
                    const float rr = v * inv + (bb[n] - mm[n] * inv);
                    out[((size_t)b * N + n) * (size_t)Mvalid + m] = rr > 0.f ? rr : 0.f;
                } else {
                    const float val = v + bias[n];
                    const int h = (n >> 5) & 7, d = n & 31;
                    if (n < 256)
                        ((unsigned short*)out)[(((size_t)b * 8 + h) * 224 + m) * 32 + d] =
                            (unsigned short)f2bf(val);
                    else
                        ((unsigned short*)out2)[(((size_t)b * 8 + h) * 32 + d) * 224 + m] =
                            (unsigned short)f2bf(val);
                }
            }
        }
    }
}

// ============================== Haar DWT ===================================
__global__ __launch_bounds__(256) void dwt_k(const float* __restrict__ in,
                                             float* __restrict__ outp)
{
    const int idx = blockIdx.x * 256 + threadIdx.x;   // 802816
    const int x = idx % 28;
    const int y = (idx / 28) % 28;
    const int c = (idx / 784) % 64;
    const int b = idx / (784 * 64);
    const float* ip = in + (size_t)(b * 64 + c) * 3136 + (2 * y) * 56 + 2 * x;
    const float a = ip[0], bb = ip[1], cc = ip[56], dd = ip[57];
    float* op = outp + (size_t)b * 200704 + (size_t)c * 784 + y * 28 + x;
    op[0]         = (a + bb + cc + dd) * 0.5f;
    op[64 * 784]  = (a - bb + cc - dd) * 0.5f;
    op[128 * 784] = (a + bb - cc - dd) * 0.5f;
    op[192 * 784] = (a - bb - cc + dd) * 0.5f;
}

// ============================== Haar IDWT -> aproj cols 256..319 ===========
__global__ __launch_bounds__(256) void idwt_k(const float* __restrict__ in,
                                              unsigned short* __restrict__ aproj)
{
    const int idx = blockIdx.x * 256 + threadIdx.x;   // 802816
    const int x = idx % 28;
    const int y = (idx / 28) % 28;
    const int c = (idx / 784) % 64;
    const int b = idx / (784 * 64);
    const float* ip = in + (size_t)b * 200704 + (size_t)c * 784 + y * 28 + x;
    const float ll = ip[0], lh = ip[64 * 784], hl = ip[128 * 784], hh = ip[192 * 784];
    const float a  = (ll + lh + hl + hh) * 0.5f;
    const float b_ = (ll - lh + hl - hh) * 0.5f;
    const float c_ = (ll + lh - hl - hh) * 0.5f;
    const float d_ = (ll - lh - hl + hh) * 0.5f;
    const int m = (2 * y) * 56 + 2 * x;
    unsigned short* op = aproj + ((size_t)b * 3200 + m) * 320 + 256 + c;
    op[0]              = (unsigned short)f2bf(a);
    op[320]            = (unsigned short)f2bf(b_);
    op[320 * 56]       = (unsigned short)f2bf(c_);
    op[320 * 56 + 320] = (unsigned short)f2bf(d_);
}

// ============================== kve im2col (2x2 s2) -> bf16 ================
__global__ __launch_bounds__(256) void im2col_kve_k(const float* __restrict__ c2,
                                                    unsigned short* __restrict__ dst)
{
    const int i = blockIdx.x * 256 + threadIdx.x;   // 1,048,576
    const int ci = i & 255;
    const int m = (i >> 8) & 255;
    const int b = i >> 16;
    unsigned int p0 = 0, p1 = 0;
    if (m < 196) {
        const int y = m / 14, x = m - 14 * y;
        const float* sp = c2 + ((size_t)(b * 256 + ci)) * 784 + (2 * y) * 28 + 2 * x;
        p0 = f2bf(sp[0])  | (f2bf(sp[1])  << 16);
        p1 = f2bf(sp[28]) | (f2bf(sp[29]) << 16);
    }
    *(uint2*)(dst + ((size_t)(b * 256 + m)) * 1024 + ci * 4) = make_uint2(p0, p1);
}

// ============================== LayerNorm -> bf16, pad rows ================
__global__ __launch_bounds__(256) void ln_k(const float* __restrict__ in,
                                            const float* __restrict__ g,
                                            const float* __restrict__ bb,
                                            unsigned short* __restrict__ outp)
{
    const int rg = blockIdx.x;            // 0..4095
    const int rl = rg & 255, b = rg >> 8;
    const int t = threadIdx.x;
    unsigned short* op = outp + (size_t)rg * 256 + t;
    if (rl >= 196) { *op = 0; return; }
    const float x = in[((size_t)(b * 196) + rl) * 256 + t];
    __shared__ float r1[4], r2[4];
    float s = x;
#pragma unroll
    for (int o = 32; o > 0; o >>= 1) s += __shfl_down(s, o);
    if ((t & 63) == 0) r1[t >> 6] = s;
    __syncthreads();
    const float mu = (r1[0] + r1[1] + r1[2] + r1[3]) * (1.f / 256.f);
    const float d = x - mu;
    float s2 = d * d;
#pragma unroll
    for (int o = 32; o > 0; o >>= 1) s2 += __shfl_down(s2, o);
    if ((t & 63) == 0) r2[t >> 6] = s2;
    __syncthreads();
    const float var = (r2[0] + r2[1] + r2[2] + r2[3]) * (1.f / 256.f);
    *op = (unsigned short)f2bf(d * rsqrtf(var + 1e-5f) * g[t] + bb[t]);
}

// ============================== MFMA attention =============================
// qb (B,8,3136,32) bf16 pre-scaled; kb (B,8,224,32) bf16 (rows>=196 garbage);
// vt (B,8,32,224) bf16 (cols>=196 garbage). Out: aproj cols 0..255 bf16.
// grid (49, 128), 256 thr = 4 waves; each wave owns 16 queries, no barriers.
// S^T = mfma(K_tile, Q^T): lane holds scores for query (lane&15),
// keys t*16 + (lane>>4)*4 + r -> row softmax = reg-reduce + shfl_xor(16,32).
__global__ __launch_bounds__(256) void attn_m(
    const unsigned short* __restrict__ qb, const unsigned short* __restrict__ kb,
    const unsigned short* __restrict__ vt, unsigned short* __restrict__ aproj)
{
    __shared__ short Pl[4][16][232];   // per-wave P: [q][key 224 + pad], 29.7 KB
    const int tid = threadIdx.x, lane = tid & 63, w = tid >> 6;
    const int bh = blockIdx.y, b = bh >> 3, h = bh & 7;
    const int q0 = blockIdx.x * 64 + w * 16;
    const int cl = lane & 15, hi = lane >> 4;

    // Q^T B-frag: lane q=cl holds Q[q][hi*8..+7]
    const bf16x8 qf = *(const bf16x8*)(qb + ((size_t)bh * 3136 + q0 + cl) * 32 + hi * 8);

    // 13 S^T tiles (keys 0..207)
    f32x4 s[13];
    const unsigned short* kp = kb + (size_t)bh * 224 * 32;
#pragma unroll
    for (int t = 0; t < 13; ++t) {
        const bf16x8 kf = *(const bf16x8*)(kp + (size_t)(t * 16 + cl) * 32 + hi * 8);
        s[t] = __builtin_amdgcn_mfma_f32_16x16x32_bf16(kf, qf,
                                                       (f32x4){0.f, 0.f, 0.f, 0.f}, 0, 0, 0);
    }
    // mask keys >= 196 (tile 12, hi>0)
    if (hi) s[12] = (f32x4){-1e30f, -1e30f, -1e30f, -1e30f};

    // row max
    float m = s[0][0];
#pragma unroll
    for (int t = 0; t < 13; ++t)
#pragma unroll
        for (int r = 0; r < 4; ++r) m = fmaxf(m, s[t][r]);
    m = fmaxf(m, __shfl_xor(m, 16));
    m = fmaxf(m, __shfl_xor(m, 32));

    // exp + row sum
    float l = 0.f;
#pragma unroll
    for (int t = 0; t < 13; ++t) {
#pragma unroll
        for (int r = 0; r < 4; ++r) { s[t][r] = __expf(s[t][r] - m); l += s[t][r]; }
    }
    l += __shfl_xor(l, 16);
    l += __shfl_xor(l, 32);
    const float rl = 1.f / l;

    // P(scaled) -> LDS, 4 consecutive keys per lane per tile
    short* prow = &Pl[w][cl][0];
#pragma unroll
    for (int t = 0; t < 13; ++t) {
        __hip_bfloat162 pa = __float22bfloat162_rn(make_float2(s[t][0] * rl, s[t][1] * rl));
        __hip_bfloat162 pb = __float22bfloat162_rn(make_float2(s[t][2] * rl, s[t][3] * rl));
        unsigned int ua, ub;
        __builtin_memcpy(&ua, &pa, 4);
        __builtin_memcpy(&ub, &pb, 4);
        *(uint2*)(prow + t * 16 + hi * 4) = make_uint2(ua, ub);
    }
    *(uint2*)(prow + 208 + hi * 4) = make_uint2(0u, 0u);   // zero keys 208..223

    // PV: O[16q][32d] = P @ V, 7 k-blocks x 2 d-tiles
    f32x4 o0 = (f32x4){0.f, 0.f, 0.f, 0.f};
    f32x4 o1 = (f32x4){0.f, 0.f, 0.f, 0.f};
    const unsigned short* vp0 = vt + ((size_t)bh * 32 + cl) * 224;
    const unsigned short* vp1 = vp0 + 16 * 224;
#pragma unroll
    for (int kk = 0; kk < 7; ++kk) {
        const bf16x8 pf = *(const bf16x8*)(prow + kk * 32 + hi * 8);
        const bf16x8 v0 = *(const bf16x8*)(vp0 + kk * 32 + hi * 8);
        const bf16x8 v1 = *(const bf16x8*)(vp1 + kk * 32 + hi * 8);
        o0 = __builtin_amdgcn_mfma_f32_16x16x32_bf16(pf, v0, o0, 0, 0, 0);
        o1 = __builtin_amdgcn_mfma_f32_16x16x32_bf16(pf, v1, o1, 0, 0, 0);
    }

    // O staging via LDS (reuse P region), then coalesced bf16 global write
    float* ol = (float*)&Pl[w][0][0];
#pragma unroll
    for (int r = 0; r < 4; ++r) {
        ol[(hi * 4 + r) * 32 + cl] = o0[r];
        ol[(hi * 4 + r) * 32 + cl + 16] = o1[r];
    }
    const int row = lane >> 2, c8 = (lane & 3) * 8;
    const float4 a0 = *(const float4*)(ol + row * 32 + c8);
    const float4 a1 = *(const float4*)(ol + row * 32 + c8 + 4);
    const unsigned int k0 = f2bf(a0.x) | (f2bf(a0.y) << 16);
    const unsigned int k1 = f2bf(a0.z) | (f2bf(a0.w) << 16);
    const unsigned int k2 = f2bf(a1.x) | (f2bf(a1.y) << 16);
    const unsigned int k3 = f2bf(a1.z) | (f2bf(a1.w) << 16);
    *(uint4*)(aproj + ((size_t)b * 3200 + q0 + row) * 320 + h * 32 + c8) =
        make_uint4(k0, k1, k2, k3);
}

// ============================== launcher ===================================
extern "C" void kernel_launch(void* const* d_in, const int* in_sizes, int n_in,
                              void* d_out, int out_size, void* d_ws, size_t ws_size,
                              hipStream_t stream)
{
    const float* x        = (const float*)d_in[0];
    const float* reduce_w = (const float*)d_in[3];
    const float* bn1_g    = (const float*)d_in[4];
    const float* bn1_b    = (const float*)d_in[5];
    const float* bn1_m    = (const float*)d_in[6];
    const float* bn1_v    = (const float*)d_in[7];
    const float* filt_w   = (const float*)d_in[8];
    const float* bn2_g    = (const float*)d_in[9];
    const float* bn2_b    = (const float*)d_in[10];
    const float* bn2_m    = (const float*)d_in[11];
    const float* bn2_v    = (const float*)d_in[12];
    const float* kve_w    = (const float*)d_in[13];
    const float* kve_b    = (const float*)d_in[14];
    const float* q_w      = (const float*)d_in[15];
    const float* q_b      = (const float*)d_in[16];
    const float* kvn_g    = (const float*)d_in[17];
    const float* kvn_b    = (const float*)d_in[18];
    const float* kv_w     = (const float*)d_in[19];
    const float* kv_b     = (const float*)d_in[20];
    const float* proj_w   = (const float*)d_in[21];
    const float* proj_b   = (const float*)d_in[22];

    float* out = (float*)d_out;
    float* ws  = (float*)d_ws;

    // ws layout (f32 units). aproj overlaps x_bf in time (x_bf dead first).
    unsigned short* aproj = (unsigned short*)ws;               // 16,384,000 us
    unsigned short* x_bf  = (unsigned short*)ws;               // 13,107,200 us
    unsigned short* a_kve = (unsigned short*)(ws + 8192000);   //  4,194,304 us
    float* bufC   = ws + 10289152;   // 3,211,264 f  (reduced / coeffs2)
    float* bufD   = ws + 13500416;   // 3,211,264 f  (coeffs)
    float* kv_src = ws + 16711680;   //   802,816 f
    unsigned short* kbuf  = (unsigned short*)(ws + 17514496);  //   917,504 us
    unsigned short* vtb   = (unsigned short*)(ws + 17973248);  //   917,504 us
    unsigned short* kv_ln = (unsigned short*)(ws + 18432000);  // 1,048,576 us
    unsigned short* wpl   = (unsigned short*)(ws + 18956288);  //   557,056 us
    unsigned short* wfilt = (unsigned short*)(ws + 19234816);  //   589,824 us
    unsigned short* wq    = wpl;
    unsigned short* wred  = wpl + 65536;
    unsigned short* wkve  = wpl + 81920;
    unsigned short* wkv   = wpl + 344064;
    unsigned short* wproj = wpl + 475136;
    unsigned short* qb    = (unsigned short*)d_out;  // bf16 Q lives in d_out

    const float scale = 0.17677669529663689f; // 1/sqrt(32)

    wcvt_k<<<544, 256, 0, stream>>>(q_w, reduce_w, kve_w, kv_w, proj_w, wpl);
    wcvt3_k<<<576, 256, 0, stream>>>(filt_w, wfilt);
    cvtx_k<<<12800, 256, 0, stream>>>(x, x_bf);

    // q = (x @ q_w^T + q_b)*scale -> qb bf16 (B,8,3136,32) in d_out
    mgemm<128, 1, 0><<<dim3(25, 2, B_), 256, 0, stream>>>(
        x_bf, nullptr, wq, q_b, nullptr, nullptr, nullptr, nullptr,
        out, nullptr, 3200, 3136, 256, 256, scale);

    // reduced = relu(bn1(x @ reduce_w^T)) -> bufC (B,64,3136)
    mgemm<64, 2, 0><<<dim3(25, 1, B_), 256, 0, stream>>>(
        x_bf, nullptr, wred, nullptr, bn1_g, bn1_b, bn1_m, bn1_v,
        bufC, nullptr, 3200, 3136, 64, 256, 0.f);

    // coeffs = dwt(reduced) -> bufD (B,256,784)
    dwt_k<<<3136, 256, 0, stream>>>(bufC, bufD);

    // coeffs2 = relu(bn2(conv3x3(coeffs))) -> bufC, implicit im2col K=2304
    mgemm<64, 2, 1><<<dim3(7, 4, B_), 256, 0, stream>>>(
        nullptr, bufD, wfilt, nullptr, bn2_g, bn2_b, bn2_m, bn2_v,
        bufC, nullptr, 896, 784, 256, 2304, 0.f);

    // local = idwt(coeffs2) -> aproj cols 256..319 (bf16)
    idwt_k<<<3136, 256, 0, stream>>>(bufC, aproj);

    // kve im2col -> a_kve (B,256,1024) bf16
    im2col_kve_k<<<4096, 256, 0, stream>>>(bufC, a_kve);

    // kv_src = im2col @ kve_w^T + kve_b -> (B,196,256) f32
    mgemm<128, 0, 0><<<dim3(2, 2, B_), 256, 0, stream>>>(
        a_kve, nullptr, wkve, kve_b, nullptr, nullptr, nullptr, nullptr,
        kv_src, nullptr, 256, 196, 256, 1024, 0.f);

    // layernorm -> kv_ln (B,256,256) bf16, zero pad rows
    ln_k<<<4096, 256, 0, stream>>>(kv_src, kvn_g, kvn_b, kv_ln);

    // kv: K bf16 (B,8,224,32), V^T bf16 (B,8,32,224)
    mgemm<128, 3, 0><<<dim3(2, 4, B_), 256, 0, stream>>>(
        kv_ln, nullptr, wkv, kv_b, nullptr, nullptr, nullptr, nullptr,
        (float*)kbuf, (float*)vtb, 256, 196, 512, 256, 0.f);

    // MFMA attention -> aproj cols 0..255 (bf16)
    attn_m<<<dim3(49, 128), 256, 0, stream>>>(qb, kbuf, vtb, aproj);

    // out = concat(att, local) @ proj_w^T + proj_b -> (B,3136,256) f32
    mgemm<128, 0, 0><<<dim3(25, 2, B_), 256, 0, stream>>>(
        aproj, nullptr, wproj, proj_b, nullptr, nullptr, nullptr, nullptr,
        out, nullptr, 3200, 3136, 256, 320, 0.f);
}

// Round 4
// 344.431 us; speedup vs baseline: 3.8759x; 1.1789x over previous
//
#include <hip/hip_runtime.h>
#include <hip/hip_bf16.h>
#include <math.h>

// ---------------------------------------------------------------------------
// WaveViT attention block. bf16 MFMA for all GEMM-shaped ops AND attention.
// B=16, Nsp=3136 (56x56), C=256, heads=8, hd=32, red=64, sr=2
// R4: dwt emits bf16 channel-last coeffs (B,784,256); conv3 im2col staging is
//     one coalesced 16B load per thread (was 8x strided f32 + cvt).
// ---------------------------------------------------------------------------

#define B_   16
#define NSP  3136
#define KVL  196
#define HD   32

typedef short bf16x8 __attribute__((ext_vector_type(8)));
typedef float f32x4  __attribute__((ext_vector_type(4)));

__device__ inline unsigned int f2bf(float f) {
    unsigned int u = __float_as_uint(f);
    u += 0x7FFFu + ((u >> 16) & 1u);
    return u >> 16;   // round-to-nearest-even bf16 bits in low 16
}

// ========================= weight conversions ==============================
__global__ __launch_bounds__(256) void wcvt_k(
    const float* __restrict__ q, const float* __restrict__ red,
    const float* __restrict__ kve, const float* __restrict__ kv,
    const float* __restrict__ proj, unsigned short* __restrict__ dst)
{
    const int i = blockIdx.x * 256 + threadIdx.x;
    const int e = i * 4;
    const float* src; int off;
    if (e < 65536)       { src = q;    off = e; }
    else if (e < 81920)  { src = red;  off = e - 65536; }
    else if (e < 344064) { src = kve;  off = e - 81920; }
    else if (e < 475136) { src = kv;   off = e - 344064; }
    else                 { src = proj; off = e - 475136; }
    const float4 v = *(const float4*)(src + off);
    const unsigned int p0 = f2bf(v.x) | (f2bf(v.y) << 16);
    const unsigned int p1 = f2bf(v.z) | (f2bf(v.w) << 16);
    *(uint2*)(dst + e) = make_uint2(p0, p1);
}

// filt_w (256,256,3,3) -> bf16 [n][k'] with k' = tap*256 + ci  (tap-major)
__global__ __launch_bounds__(256) void wcvt3_k(const float* __restrict__ filt,
                                               unsigned short* __restrict__ wf)
{
    const int i = blockIdx.x * 256 + threadIdx.x;   // 147456 = 576*256
    const int n = i / 576;
    const int rem = (i - n * 576) * 4;
    const int tap = rem >> 8;
    const int ci = rem & 255;
    const float* s = filt + (size_t)n * 2304;
    const unsigned int t0 = f2bf(s[(ci + 0) * 9 + tap]);
    const unsigned int t1 = f2bf(s[(ci + 1) * 9 + tap]);
    const unsigned int t2 = f2bf(s[(ci + 2) * 9 + tap]);
    const unsigned int t3 = f2bf(s[(ci + 3) * 9 + tap]);
    *(uint2*)(wf + (size_t)n * 2304 + rem) = make_uint2(t0 | (t1 << 16), t2 | (t3 << 16));
}

// x (B,3136,256) f32 -> x_bf (B,3200,256) bf16, zero pad rows
__global__ __launch_bounds__(256) void cvtx_k(const float* __restrict__ x,
                                              unsigned short* __restrict__ xb)
{
    const int i = blockIdx.x * 256 + threadIdx.x;   // 3,276,800
    const int c4 = (i & 63) * 4;
    const int row = (i >> 6) % 3200;
    const int b = (i >> 6) / 3200;
    unsigned int p0 = 0, p1 = 0;
    if (row < 3136) {
        const float4 v = *(const float4*)(x + ((size_t)(b * 3136 + row)) * 256 + c4);
        p0 = f2bf(v.x) | (f2bf(v.y) << 16);
        p1 = f2bf(v.z) | (f2bf(v.w) << 16);
    }
    *(uint2*)(xb + ((size_t)(b * 3200) + row) * 256 + c4) = make_uint2(p0, p1);
}

// ============================ MFMA GEMM ====================================
// C[m,n] = sum_k A[m,k]*W[n,k]. BM=128, BK=32, 4 waves (2x2), 16x16x32 bf16.
// LDM 0: A = bf16 [B][Mpad][K] row-major.
// LDM 1: implicit im2col 3x3 pad1, A = bf16 channel-last (B,784,256),
//        K order k' = tap*256 + ci; one 16B coalesced load per thread.
// EPI 0: out[(b*Mv+m)*N+n] = v + bias[n]                   (f32 row-major)
// EPI 1: bf16 head-major Q: qb[((b*8+h)*3136+m)*32+d] = (v+bias)*scale
// EPI 2: out[(b*N+n)*Mv+m] = relu(BN(v))                   (f32 transposed)
// EPI 3: bf16 K (b,h,224,32) / V^T (b,h,32,224) split
template<int BN, int EPI, int LDM>
__global__ __launch_bounds__(256) void mgemm(
    const unsigned short* __restrict__ A, const unsigned short* __restrict__ Acl,
    const unsigned short* __restrict__ W, const float* __restrict__ bias,
    const float* __restrict__ g, const float* __restrict__ bb,
    const float* __restrict__ mm, const float* __restrict__ vv,
    float* __restrict__ out, float* __restrict__ out2,
    int Mpad, int Mvalid, int N, int K, float scale)
{
    constexpr int FN = BN / 32;
    __shared__ short As[128][32];
    __shared__ short Bs[BN][32];
    const int tid = threadIdx.x, lane = tid & 63;
    const int w = tid >> 6, wr = w >> 1, wc = w & 1;
    const int b = blockIdx.z, m0 = blockIdx.x * 128, n0 = blockIdx.y * BN;
    const unsigned short* Ab = A + ((size_t)b * Mpad + m0) * (size_t)K;
    const unsigned short* Wb = W + (size_t)n0 * K;

    const int r_row0 = tid >> 2, r_c16 = tid & 3;
    int ym[2], xm[2], mm_[2];
#pragma unroll
    for (int rnd = 0; rnd < 2; ++rnd) {
        const int m = m0 + rnd * 64 + r_row0;
        mm_[rnd] = m;
        ym[rnd] = m / 28;
        xm[rnd] = m - 28 * ym[rnd];
    }

    f32x4 acc[4][FN];
#pragma unroll
    for (int i = 0; i < 4; ++i)
#pragma unroll
        for (int j = 0; j < FN; ++j) acc[i][j] = (f32x4){0.f, 0.f, 0.f, 0.f};

    for (int k0 = 0; k0 < K; k0 += 32) {
#pragma unroll
        for (int rnd = 0; rnd < 2; ++rnd) {
            const int row = rnd * 64 + r_row0;
            if constexpr (LDM == 0) {
                *(int4*)&As[row][r_c16 * 8] =
                    *(const int4*)(Ab + (size_t)row * K + k0 + r_c16 * 8);
            } else {
                const int kk = k0 + r_c16 * 8;
                const int tap = kk >> 8;          // constant within a k0 tile
                const int ci0 = kk & 255;
                const int ky = tap / 3, kx = tap - 3 * ky;
                const int sy = ym[rnd] + ky - 1, sx = xm[rnd] + kx - 1;
                int4 v = make_int4(0, 0, 0, 0);
                if (mm_[rnd] < Mvalid && sy >= 0 && sy < 28 && sx >= 0 && sx < 28)
                    v = *(const int4*)(Acl + ((size_t)b * 784 + sy * 28 + sx) * 256 + ci0);
                *(int4*)&As[row][r_c16 * 8] = v;
            }
        }
#pragma unroll
        for (int rnd = 0; rnd < BN / 64; ++rnd) {
            const int row = rnd * 64 + r_row0;
            *(int4*)&Bs[row][r_c16 * 8] =
                *(const int4*)(Wb + (size_t)row * K + k0 + r_c16 * 8);
        }
        __syncthreads();
        bf16x8 af[4], bfr[FN];
#pragma unroll
        for (int i = 0; i < 4; ++i)
            af[i] = *(const bf16x8*)&As[wr * 64 + i * 16 + (lane & 15)][(lane >> 4) * 8];
#pragma unroll
        for (int j = 0; j < FN; ++j)
            bfr[j] = *(const bf16x8*)&Bs[wc * (FN * 16) + j * 16 + (lane & 15)][(lane >> 4) * 8];
#pragma unroll
        for (int i = 0; i < 4; ++i)
#pragma unroll
            for (int j = 0; j < FN; ++j)
                acc[i][j] = __builtin_amdgcn_mfma_f32_16x16x32_bf16(af[i], bfr[j], acc[i][j], 0, 0, 0);
        __syncthreads();
    }

    const int cl = lane & 15, rh = lane >> 4;
#pragma unroll
    for (int i = 0; i < 4; ++i) {
#pragma unroll
        for (int j = 0; j < FN; ++j) {
            const int n = n0 + wc * (FN * 16) + j * 16 + cl;
#pragma unroll
            for (int r = 0; r < 4; ++r) {
                const int m = m0 + wr * 64 + i * 16 + rh * 4 + r;
                if (m >= Mvalid) continue;
                const float v = acc[i][j][r];
                if constexpr (EPI == 0) {
                    out[((size_t)b * Mvalid + m) * N + n] = v + bias[n];
                } else if constexpr (EPI == 1) {
                    unsigned short* qp = (unsigned short*)out;
                    const int h = (n >> 5) & 7, d = n & 31;
                    qp[(((size_t)b * 8 + h) * 3136 + m) * 32 + d] =
                        (unsigned short)f2bf((v + bias[n]) * scale);
                } else if constexpr (EPI == 2) {
                    const float inv = g[n] * rsqrtf(vv[n] + 1e-5f);
                    const float rr = v * inv + (bb[n] - mm[n] * inv);
                    out[((size_t)b * N + n) * (size_t)Mvalid + m] = rr > 0.f ? rr : 0.f;
                } else {
                    const float val = v + bias[n];
                    const int h = (n >> 5) & 7, d = n & 31;
                    if (n < 256)
                        ((unsigned short*)out)[(((size_t)b * 8 + h) * 224 + m) * 32 + d] =
                            (unsigned short)f2bf(val);
                    else
                        ((unsigned short*)out2)[(((size_t)b * 8 + h) * 32 + d) * 224 + m] =
                            (unsigned short)f2bf(val);
                }
            }
        }
    }
}

// ============================== Haar DWT -> bf16 channel-last ==============
// reduced f32 (B,64,3136) channel-major -> cl bf16 (B,784,256), c' = sb*64+c.
// grid (7,16) x 256 thr: thread = (y = bx*4 + tid>>6, c = tid&63, b = by).
// Reads per-lane contiguous rows; writes 64-lane 128B segments.
__global__ __launch_bounds__(256) void dwt_k(const float* __restrict__ in,
                                             unsigned short* __restrict__ cl)
{
    const int c = threadIdx.x & 63;
    const int y = blockIdx.x * 4 + (threadIdx.x >> 6);
    const int b = blockIdx.y;
    const float* ip = in + ((size_t)(b * 64 + c)) * 3136 + (2 * y) * 56;
    unsigned short* op = cl + ((size_t)b * 784 + y * 28) * 256 + c;
#pragma unroll
    for (int x = 0; x < 28; ++x) {
        const float a  = ip[2 * x],      bb = ip[2 * x + 1];
        const float cc = ip[2 * x + 56], dd = ip[2 * x + 57];
        op[x * 256 + 0]   = (unsigned short)f2bf((a + bb + cc + dd) * 0.5f);
        op[x * 256 + 64]  = (unsigned short)f2bf((a - bb + cc - dd) * 0.5f);
        op[x * 256 + 128] = (unsigned short)f2bf((a + bb - cc - dd) * 0.5f);
        op[x * 256 + 192] = (unsigned short)f2bf((a - bb - cc + dd) * 0.5f);
    }
}

// ============================== Haar IDWT -> aproj cols 256..319 ===========
__global__ __launch_bounds__(256) void idwt_k(const float* __restrict__ in,
                                              unsigned short* __restrict__ aproj)
{
    const int idx = blockIdx.x * 256 + threadIdx.x;   // 802816
    const int x = idx % 28;
    const int y = (idx / 28) % 28;
    const int c = (idx / 784) % 64;
    const int b = idx / (784 * 64);
    const float* ip = in + (size_t)b * 200704 + (size_t)c * 784 + y * 28 + x;
    const float ll = ip[0], lh = ip[64 * 784], hl = ip[128 * 784], hh = ip[192 * 784];
    const float a  = (ll + lh + hl + hh) * 0.5f;
    const float b_ = (ll - lh + hl - hh) * 0.5f;
    const float c_ = (ll + lh - hl - hh) * 0.5f;
    const float d_ = (ll - lh - hl + hh) * 0.5f;
    const int m = (2 * y) * 56 + 2 * x;
    unsigned short* op = aproj + ((size_t)b * 3200 + m) * 320 + 256 + c;
    op[0]              = (unsigned short)f2bf(a);
    op[320]            = (unsigned short)f2bf(b_);
    op[320 * 56]       = (unsigned short)f2bf(c_);
    op[320 * 56 + 320] = (unsigned short)f2bf(d_);
}

// ============================== kve im2col (2x2 s2) -> bf16 ================
__global__ __launch_bounds__(256) void im2col_kve_k(const float* __restrict__ c2,
                                                    unsigned short* __restrict__ dst)
{
    const int i = blockIdx.x * 256 + threadIdx.x;   // 1,048,576
    const int ci = i & 255;
    const int m = (i >> 8) & 255;
    const int b = i >> 16;
    unsigned int p0 = 0, p1 = 0;
    if (m < 196) {
        const int y = m / 14, x = m - 14 * y;
        const float* sp = c2 + ((size_t)(b * 256 + ci)) * 784 + (2 * y) * 28 + 2 * x;
        p0 = f2bf(sp[0])  | (f2bf(sp[1])  << 16);
        p1 = f2bf(sp[28]) | (f2bf(sp[29]) << 16);
    }
    *(uint2*)(dst + ((size_t)(b * 256 + m)) * 1024 + ci * 4) = make_uint2(p0, p1);
}

// ============================== LayerNorm -> bf16, pad rows ================
__global__ __launch_bounds__(256) void ln_k(const float* __restrict__ in,
                                            const float* __restrict__ g,
                                            const float* __restrict__ bb,
                                            unsigned short* __restrict__ outp)
{
    const int rg = blockIdx.x;            // 0..4095
    const int rl = rg & 255, b = rg >> 8;
    const int t = threadIdx.x;
    unsigned short* op = outp + (size_t)rg * 256 + t;
    if (rl >= 196) { *op = 0; return; }
    const float x = in[((size_t)(b * 196) + rl) * 256 + t];
    __shared__ float r1[4], r2[4];
    float s = x;
#pragma unroll
    for (int o = 32; o > 0; o >>= 1) s += __shfl_down(s, o);
    if ((t & 63) == 0) r1[t >> 6] = s;
    __syncthreads();
    const float mu = (r1[0] + r1[1] + r1[2] + r1[3]) * (1.f / 256.f);
    const float d = x - mu;
    float s2 = d * d;
#pragma unroll
    for (int o = 32; o > 0; o >>= 1) s2 += __shfl_down(s2, o);
    if ((t & 63) == 0) r2[t >> 6] = s2;
    __syncthreads();
    const float var = (r2[0] + r2[1] + r2[2] + r2[3]) * (1.f / 256.f);
    *op = (unsigned short)f2bf(d * rsqrtf(var + 1e-5f) * g[t] + bb[t]);
}

// ============================== MFMA attention =============================
__global__ __launch_bounds__(256) void attn_m(
    const unsigned short* __restrict__ qb, const unsigned short* __restrict__ kb,
    const unsigned short* __restrict__ vt, unsigned short* __restrict__ aproj)
{
    __shared__ short Pl[4][16][232];   // per-wave P: [q][key 224 + pad], 29.7 KB
    const int tid = threadIdx.x, lane = tid & 63, w = tid >> 6;
    const int bh = blockIdx.y, b = bh >> 3, h = bh & 7;
    const int q0 = blockIdx.x * 64 + w * 16;
    const int cl = lane & 15, hi = lane >> 4;

    const bf16x8 qf = *(const bf16x8*)(qb + ((size_t)bh * 3136 + q0 + cl) * 32 + hi * 8);

    f32x4 s[13];
    const unsigned short* kp = kb + (size_t)bh * 224 * 32;
#pragma unroll
    for (int t = 0; t < 13; ++t) {
        const bf16x8 kf = *(const bf16x8*)(kp + (size_t)(t * 16 + cl) * 32 + hi * 8);
        s[t] = __builtin_amdgcn_mfma_f32_16x16x32_bf16(kf, qf,
                                                       (f32x4){0.f, 0.f, 0.f, 0.f}, 0, 0, 0);
    }
    if (hi) s[12] = (f32x4){-1e30f, -1e30f, -1e30f, -1e30f};

    float m = s[0][0];
#pragma unroll
    for (int t = 0; t < 13; ++t)
#pragma unroll
        for (int r = 0; r < 4; ++r) m = fmaxf(m, s[t][r]);
    m = fmaxf(m, __shfl_xor(m, 16));
    m = fmaxf(m, __shfl_xor(m, 32));

    float l = 0.f;
#pragma unroll
    for (int t = 0; t < 13; ++t) {
#pragma unroll
        for (int r = 0; r < 4; ++r) { s[t][r] = __expf(s[t][r] - m); l += s[t][r]; }
    }
    l += __shfl_xor(l, 16);
    l += __shfl_xor(l, 32);
    const float rl = 1.f / l;

    short* prow = &Pl[w][cl][0];
#pragma unroll
    for (int t = 0; t < 13; ++t) {
        __hip_bfloat162 pa = __float22bfloat162_rn(make_float2(s[t][0] * rl, s[t][1] * rl));
        __hip_bfloat162 pb = __float22bfloat162_rn(make_float2(s[t][2] * rl, s[t][3] * rl));
        unsigned int ua, ub;
        __builtin_memcpy(&ua, &pa, 4);
        __builtin_memcpy(&ub, &pb, 4);
        *(uint2*)(prow + t * 16 + hi * 4) = make_uint2(ua, ub);
    }
    *(uint2*)(prow + 208 + hi * 4) = make_uint2(0u, 0u);

    f32x4 o0 = (f32x4){0.f, 0.f, 0.f, 0.f};
    f32x4 o1 = (f32x4){0.f, 0.f, 0.f, 0.f};
    const unsigned short* vp0 = vt + ((size_t)bh * 32 + cl) * 224;
    const unsigned short* vp1 = vp0 + 16 * 224;
#pragma unroll
    for (int kk = 0; kk < 7; ++kk) {
        const bf16x8 pf = *(const bf16x8*)(prow + kk * 32 + hi * 8);
        const bf16x8 v0 = *(const bf16x8*)(vp0 + kk * 32 + hi * 8);
        const bf16x8 v1 = *(const bf16x8*)(vp1 + kk * 32 + hi * 8);
        o0 = __builtin_amdgcn_mfma_f32_16x16x32_bf16(pf, v0, o0, 0, 0, 0);
        o1 = __builtin_amdgcn_mfma_f32_16x16x32_bf16(pf, v1, o1, 0, 0, 0);
    }

    float* ol = (float*)&Pl[w][0][0];
#pragma unroll
    for (int r = 0; r < 4; ++r) {
        ol[(hi * 4 + r) * 32 + cl] = o0[r];
        ol[(hi * 4 + r) * 32 + cl + 16] = o1[r];
    }
    const int row = lane >> 2, c8 = (lane & 3) * 8;
    const float4 a0 = *(const float4*)(ol + row * 32 + c8);
    const float4 a1 = *(const float4*)(ol + row * 32 + c8 + 4);
    const unsigned int k0 = f2bf(a0.x) | (f2bf(a0.y) << 16);
    const unsigned int k1 = f2bf(a0.z) | (f2bf(a0.w) << 16);
    const unsigned int k2 = f2bf(a1.x) | (f2bf(a1.y) << 16);
    const unsigned int k3 = f2bf(a1.z) | (f2bf(a1.w) << 16);
    *(uint4*)(aproj + ((size_t)b * 3200 + q0 + row) * 320 + h * 32 + c8) =
        make_uint4(k0, k1, k2, k3);
}

// ============================== launcher ===================================
extern "C" void kernel_launch(void* const* d_in, const int* in_sizes, int n_in,
                              void* d_out, int out_size, void* d_ws, size_t ws_size,
                              hipStream_t stream)
{
    const float* x        = (const float*)d_in[0];
    const float* reduce_w = (const float*)d_in[3];
    const float* bn1_g    = (const float*)d_in[4];
    const float* bn1_b    = (const float*)d_in[5];
    const float* bn1_m    = (const float*)d_in[6];
    const float* bn1_v    = (const float*)d_in[7];
    const float* filt_w   = (const float*)d_in[8];
    const float* bn2_g    = (const float*)d_in[9];
    const float* bn2_b    = (const float*)d_in[10];
    const float* bn2_m    = (const float*)d_in[11];
    const float* bn2_v    = (const float*)d_in[12];
    const float* kve_w    = (const float*)d_in[13];
    const float* kve_b    = (const float*)d_in[14];
    const float* q_w      = (const float*)d_in[15];
    const float* q_b      = (const float*)d_in[16];
    const float* kvn_g    = (const float*)d_in[17];
    const float* kvn_b    = (const float*)d_in[18];
    const float* kv_w     = (const float*)d_in[19];
    const float* kv_b     = (const float*)d_in[20];
    const float* proj_w   = (const float*)d_in[21];
    const float* proj_b   = (const float*)d_in[22];

    float* out = (float*)d_out;
    float* ws  = (float*)d_ws;

    // ws layout (f32 units). aproj overlaps x_bf in time (x_bf dead first).
    unsigned short* aproj = (unsigned short*)ws;               // 16,384,000 us
    unsigned short* x_bf  = (unsigned short*)ws;               // 13,107,200 us
    unsigned short* a_kve = (unsigned short*)(ws + 8192000);   //  4,194,304 us
    float* bufC   = ws + 10289152;   // 3,211,264 f  (reduced / coeffs2)
    unsigned short* ccl = (unsigned short*)(ws + 13500416);    // 3,211,264 us (coeffs cl)
    float* kv_src = ws + 16711680;   //   802,816 f
    unsigned short* kbuf  = (unsigned short*)(ws + 17514496);  //   917,504 us
    unsigned short* vtb   = (unsigned short*)(ws + 17973248);  //   917,504 us
    unsigned short* kv_ln = (unsigned short*)(ws + 18432000);  // 1,048,576 us
    unsigned short* wpl   = (unsigned short*)(ws + 18956288);  //   557,056 us
    unsigned short* wfilt = (unsigned short*)(ws + 19234816);  //   589,824 us
    unsigned short* wq    = wpl;
    unsigned short* wred  = wpl + 65536;
    unsigned short* wkve  = wpl + 81920;
    unsigned short* wkv   = wpl + 344064;
    unsigned short* wproj = wpl + 475136;
    unsigned short* qb    = (unsigned short*)d_out;  // bf16 Q lives in d_out

    const float scale = 0.17677669529663689f; // 1/sqrt(32)

    wcvt_k<<<544, 256, 0, stream>>>(q_w, reduce_w, kve_w, kv_w, proj_w, wpl);
    wcvt3_k<<<576, 256, 0, stream>>>(filt_w, wfilt);
    cvtx_k<<<12800, 256, 0, stream>>>(x, x_bf);

    // q = (x @ q_w^T + q_b)*scale -> qb bf16 (B,8,3136,32) in d_out
    mgemm<128, 1, 0><<<dim3(25, 2, B_), 256, 0, stream>>>(
        x_bf, nullptr, wq, q_b, nullptr, nullptr, nullptr, nullptr,
        out, nullptr, 3200, 3136, 256, 256, scale);

    // reduced = relu(bn1(x @ reduce_w^T)) -> bufC (B,64,3136)
    mgemm<64, 2, 0><<<dim3(25, 1, B_), 256, 0, stream>>>(
        x_bf, nullptr, wred, nullptr, bn1_g, bn1_b, bn1_m, bn1_v,
        bufC, nullptr, 3200, 3136, 64, 256, 0.f);

    // coeffs = dwt(reduced) -> ccl bf16 channel-last (B,784,256)
    dwt_k<<<dim3(7, B_), 256, 0, stream>>>(bufC, ccl);

    // coeffs2 = relu(bn2(conv3x3(coeffs))) -> bufC, implicit im2col K=2304
    mgemm<64, 2, 1><<<dim3(7, 4, B_), 256, 0, stream>>>(
        nullptr, ccl, wfilt, nullptr, bn2_g, bn2_b, bn2_m, bn2_v,
        bufC, nullptr, 896, 784, 256, 2304, 0.f);

    // local = idwt(coeffs2) -> aproj cols 256..319 (bf16)
    idwt_k<<<3136, 256, 0, stream>>>(bufC, aproj);

    // kve im2col -> a_kve (B,256,1024) bf16
    im2col_kve_k<<<4096, 256, 0, stream>>>(bufC, a_kve);

    // kv_src = im2col @ kve_w^T + kve_b -> (B,196,256) f32
    mgemm<128, 0, 0><<<dim3(2, 2, B_), 256, 0, stream>>>(
        a_kve, nullptr, wkve, kve_b, nullptr, nullptr, nullptr, nullptr,
        kv_src, nullptr, 256, 196, 256, 1024, 0.f);

    // layernorm -> kv_ln (B,256,256) bf16, zero pad rows
    ln_k<<<4096, 256, 0, stream>>>(kv_src, kvn_g, kvn_b, kv_ln);

    // kv: K bf16 (B,8,224,32), V^T bf16 (B,8,32,224)
    mgemm<128, 3, 0><<<dim3(2, 4, B_), 256, 0, stream>>>(
        kv_ln, nullptr, wkv, kv_b, nullptr, nullptr, nullptr, nullptr,
        (float*)kbuf, (float*)vtb, 256, 196, 512, 256, 0.f);

    // MFMA attention -> aproj cols 0..255 (bf16)
    attn_m<<<dim3(49, 128), 256, 0, stream>>>(qb, kbuf, vtb, aproj);

    // out = concat(att, local) @ proj_w^T + proj_b -> (B,3136,256) f32
    mgemm<128, 0, 0><<<dim3(25, 2, B_), 256, 0, stream>>>(
        aproj, nullptr, wproj, proj_b, nullptr, nullptr, nullptr, nullptr,
        out, nullptr, 3200, 3136, 256, 320, 0.f);
}

// Round 5
// 268.478 us; speedup vs baseline: 4.9724x; 1.2829x over previous
//
#include <hip/hip_runtime.h>
#include <hip/hip_bf16.h>
#include <math.h>

// ---------------------------------------------------------------------------
// WaveViT attention block. bf16 MFMA everywhere GEMM-shaped; fused layouts.
// B=16, Nsp=3136 (56x56), C=256, heads=8, hd=32, red=64, sr=2
// R5: BM templated (64 for small-M GEMMs -> 2-4x grid), channel-last bf16
//     chain reduce->dwt->conv3->idwt/kv_src (drops cvtx + im2col passes).
// ---------------------------------------------------------------------------

#define B_   16
#define NSP  3136
#define KVL  196
#define HD   32

typedef short bf16x8 __attribute__((ext_vector_type(8)));
typedef float f32x4  __attribute__((ext_vector_type(4)));

__device__ inline unsigned int f2bf(float f) {
    unsigned int u = __float_as_uint(f);
    u += 0x7FFFu + ((u >> 16) & 1u);
    return u >> 16;
}
__device__ inline float bf2f(unsigned short u) {
    return __uint_as_float(((unsigned int)u) << 16);
}

// ========================= weight conversions ==============================
// q_w(65536), reduce_w(16384), kv_w(131072), proj_w(81920) -> wpl
__global__ __launch_bounds__(256) void wcvt_k(
    const float* __restrict__ q, const float* __restrict__ red,
    const float* __restrict__ kv, const float* __restrict__ proj,
    unsigned short* __restrict__ dst)
{
    const int i = blockIdx.x * 256 + threadIdx.x;   // 73728 threads
    const int e = i * 4;
    const float* src; int off;
    if (e < 65536)       { src = q;    off = e; }
    else if (e < 81920)  { src = red;  off = e - 65536; }
    else if (e < 212992) { src = kv;   off = e - 81920; }
    else                 { src = proj; off = e - 212992; }
    const float4 v = *(const float4*)(src + off);
    const unsigned int p0 = f2bf(v.x) | (f2bf(v.y) << 16);
    const unsigned int p1 = f2bf(v.z) | (f2bf(v.w) << 16);
    *(uint2*)(dst + e) = make_uint2(p0, p1);
}

// kve_w (256,256,2,2) -> bf16 [n][k'] k' = tap*256 + ci (tap-major)
__global__ __launch_bounds__(256) void wcvt2_k(const float* __restrict__ kve,
                                               unsigned short* __restrict__ wk)
{
    const int i = blockIdx.x * 256 + threadIdx.x;   // 65536
    const int n = i >> 8;
    const int rem = i & 255;
    const int tap = rem >> 6;
    const int ci0 = (rem & 63) * 4;
    const float* s = kve + (size_t)n * 1024;
    const unsigned int t0 = f2bf(s[(ci0 + 0) * 4 + tap]);
    const unsigned int t1 = f2bf(s[(ci0 + 1) * 4 + tap]);
    const unsigned int t2 = f2bf(s[(ci0 + 2) * 4 + tap]);
    const unsigned int t3 = f2bf(s[(ci0 + 3) * 4 + tap]);
    *(uint2*)(wk + (size_t)n * 1024 + tap * 256 + ci0) =
        make_uint2(t0 | (t1 << 16), t2 | (t3 << 16));
}

// filt_w (256,256,3,3) -> bf16 [n][k'] k' = tap*256 + ci (tap-major)
__global__ __launch_bounds__(256) void wcvt3_k(const float* __restrict__ filt,
                                               unsigned short* __restrict__ wf)
{
    const int i = blockIdx.x * 256 + threadIdx.x;   // 147456
    const int n = i / 576;
    const int rem = (i - n * 576) * 4;
    const int tap = rem >> 8;
    const int ci = rem & 255;
    const float* s = filt + (size_t)n * 2304;
    const unsigned int t0 = f2bf(s[(ci + 0) * 9 + tap]);
    const unsigned int t1 = f2bf(s[(ci + 1) * 9 + tap]);
    const unsigned int t2 = f2bf(s[(ci + 2) * 9 + tap]);
    const unsigned int t3 = f2bf(s[(ci + 3) * 9 + tap]);
    *(uint2*)(wf + (size_t)n * 2304 + rem) = make_uint2(t0 | (t1 << 16), t2 | (t3 << 16));
}

// ============================ MFMA GEMM ====================================
// C[m,n] = sum_k A[m,k]*W[n,k]. BK=32, 4 waves (2x2), 16x16x32 bf16.
// LDM 0: A bf16 [B][Mpad][K] row-major
// LDM 1: implicit im2col 3x3 pad1 from Acl bf16 (B,784=28x28,256), k'=tap*256+ci
// LDM 2: A f32 [B][Mvalid][K] row-major, convert in staging (for x)
// LDM 3: implicit im2col 2x2 s2 from Acl bf16 (B,784,256), out 14x14, k'=tap*256+ci
// EPI 0: f32 out[(b*Mv+m)*N+n] = v + bias[n]
// EPI 1: bf16 head-major Q: out[((b*8+h)*3136+m)*32+d] = (v+bias)*scale
// EPI 3: bf16 K (b,h,224,32) / V^T (b,h,32,224) split (+bias)
// EPI 4: bf16 channel-last BN+ReLU: out[((b*Mv+m)*N+n] = relu(BN(v))
template<int BM, int BN, int EPI, int LDM>
__global__ __launch_bounds__(256) void mgemm(
    const unsigned short* __restrict__ A, const float* __restrict__ Af,
    const unsigned short* __restrict__ Acl,
    const unsigned short* __restrict__ W, const float* __restrict__ bias,
    const float* __restrict__ g, const float* __restrict__ bb,
    const float* __restrict__ mm, const float* __restrict__ vv,
    float* __restrict__ out, float* __restrict__ out2,
    int Mpad, int Mvalid, int N, int K, float scale)
{
    constexpr int FM = BM / 32, FN = BN / 32;
    constexpr int RA = BM / 64, RB = BN / 64;
    __shared__ short As[BM][32];
    __shared__ short Bs[BN][32];
    const int tid = threadIdx.x, lane = tid & 63;
    const int w = tid >> 6, wr = w >> 1, wc = w & 1;
    const int b = blockIdx.z, m0 = blockIdx.x * BM, n0 = blockIdx.y * BN;
    const unsigned short* Ab = A + ((size_t)b * Mpad + m0) * (size_t)K;
    const unsigned short* Wb = W + (size_t)n0 * K;

    const int r_row0 = tid >> 2, kbase = (tid & 3) * 8;
    int ym[RA], xm[RA], mg[RA];
#pragma unroll
    for (int rnd = 0; rnd < RA; ++rnd) {
        const int m = m0 + rnd * 64 + r_row0;
        mg[rnd] = m;
        if constexpr (LDM == 1) { ym[rnd] = m / 28; xm[rnd] = m - 28 * ym[rnd]; }
        else if constexpr (LDM == 3) { ym[rnd] = m / 14; xm[rnd] = m - 14 * ym[rnd]; }
        else { ym[rnd] = 0; xm[rnd] = 0; }
    }

    f32x4 acc[FM][FN];
#pragma unroll
    for (int i = 0; i < FM; ++i)
#pragma unroll
        for (int j = 0; j < FN; ++j) acc[i][j] = (f32x4){0.f, 0.f, 0.f, 0.f};

    for (int k0 = 0; k0 < K; k0 += 32) {
        // ---- stage A
#pragma unroll
        for (int rnd = 0; rnd < RA; ++rnd) {
            const int row = rnd * 64 + r_row0;
            if constexpr (LDM == 0) {
                *(int4*)&As[row][kbase] =
                    *(const int4*)(Ab + (size_t)row * K + k0 + kbase);
            } else if constexpr (LDM == 2) {
                unsigned int p0 = 0, p1 = 0, p2 = 0, p3 = 0;
                if (mg[rnd] < Mvalid) {
                    const float* sp = Af + ((size_t)b * Mvalid + mg[rnd]) * K + k0 + kbase;
                    const float4 v0 = *(const float4*)sp;
                    const float4 v1 = *(const float4*)(sp + 4);
                    p0 = f2bf(v0.x) | (f2bf(v0.y) << 16);
                    p1 = f2bf(v0.z) | (f2bf(v0.w) << 16);
                    p2 = f2bf(v1.x) | (f2bf(v1.y) << 16);
                    p3 = f2bf(v1.z) | (f2bf(v1.w) << 16);
                }
                *(int4*)&As[row][kbase] = make_int4(p0, p1, p2, p3);
            } else if constexpr (LDM == 1) {
                const int kk = k0 + kbase;
                const int tap = kk >> 8, ci0 = kk & 255;
                const int ky = tap / 3, kx = tap - 3 * ky;
                const int sy = ym[rnd] + ky - 1, sx = xm[rnd] + kx - 1;
                int4 v = make_int4(0, 0, 0, 0);
                if (mg[rnd] < Mvalid && sy >= 0 && sy < 28 && sx >= 0 && sx < 28)
                    v = *(const int4*)(Acl + ((size_t)b * 784 + sy * 28 + sx) * 256 + ci0);
                *(int4*)&As[row][kbase] = v;
            } else { // LDM == 3
                const int kk = k0 + kbase;
                const int tap = kk >> 8, ci0 = kk & 255;
                const int ky = tap >> 1, kx = tap & 1;
                const int sy = 2 * ym[rnd] + ky, sx = 2 * xm[rnd] + kx;
                int4 v = make_int4(0, 0, 0, 0);
                if (mg[rnd] < Mvalid)
                    v = *(const int4*)(Acl + ((size_t)b * 784 + sy * 28 + sx) * 256 + ci0);
                *(int4*)&As[row][kbase] = v;
            }
        }
        // ---- stage B
#pragma unroll
        for (int rnd = 0; rnd < RB; ++rnd) {
            const int row = rnd * 64 + r_row0;
            *(int4*)&Bs[row][kbase] =
                *(const int4*)(Wb + (size_t)row * K + k0 + kbase);
        }
        __syncthreads();
        bf16x8 af[FM], bfr[FN];
#pragma unroll
        for (int i = 0; i < FM; ++i)
            af[i] = *(const bf16x8*)&As[wr * (BM / 2) + i * 16 + (lane & 15)][(lane >> 4) * 8];
#pragma unroll
        for (int j = 0; j < FN; ++j)
            bfr[j] = *(const bf16x8*)&Bs[wc * (BN / 2) + j * 16 + (lane & 15)][(lane >> 4) * 8];
#pragma unroll
        for (int i = 0; i < FM; ++i)
#pragma unroll
            for (int j = 0; j < FN; ++j)
                acc[i][j] = __builtin_amdgcn_mfma_f32_16x16x32_bf16(af[i], bfr[j], acc[i][j], 0, 0, 0);
        __syncthreads();
    }

    const int cl = lane & 15, rh = lane >> 4;
#pragma unroll
    for (int i = 0; i < FM; ++i) {
#pragma unroll
        for (int j = 0; j < FN; ++j) {
            const int n = n0 + wc * (BN / 2) + j * 16 + cl;
#pragma unroll
            for (int r = 0; r < 4; ++r) {
                const int m = m0 + wr * (BM / 2) + i * 16 + rh * 4 + r;
                if (m >= Mvalid) continue;
                const float v = acc[i][j][r];
                if constexpr (EPI == 0) {
                    out[((size_t)b * Mvalid + m) * N + n] = v + bias[n];
                } else if constexpr (EPI == 1) {
                    unsigned short* qp = (unsigned short*)out;
                    const int h = (n >> 5) & 7, d = n & 31;
                    qp[(((size_t)b * 8 + h) * 3136 + m) * 32 + d] =
                        (unsigned short)f2bf((v + bias[n]) * scale);
                } else if constexpr (EPI == 3) {
                    const float val = v + bias[n];
                    const int h = (n >> 5) & 7, d = n & 31;
                    if (n < 256)
                        ((unsigned short*)out)[(((size_t)b * 8 + h) * 224 + m) * 32 + d] =
                            (unsigned short)f2bf(val);
                    else
                        ((unsigned short*)out2)[(((size_t)b * 8 + h) * 32 + d) * 224 + m] =
                            (unsigned short)f2bf(val);
                } else { // EPI == 4
                    const float inv = g[n] * rsqrtf(vv[n] + 1e-5f);
                    const float rr = v * inv + (bb[n] - mm[n] * inv);
                    ((unsigned short*)out)[((size_t)b * Mvalid + m) * N + n] =
                        (unsigned short)f2bf(rr > 0.f ? rr : 0.f);
                }
            }
        }
    }
}

// ============================== Haar DWT ===================================
// rd_cl bf16 (B,3136,64) channel-last -> ccl bf16 (B,784,256), c' = sb*64+c
__global__ __launch_bounds__(256) void dwt_k(const unsigned short* __restrict__ rd,
                                             unsigned short* __restrict__ ccl)
{
    const int i = blockIdx.x * 256 + threadIdx.x;   // 200704
    const int c4 = (i & 15) * 4;
    const int p = i >> 4;
    const int x = p % 28, y = (p / 28) % 28, b = p / 784;
    const unsigned short* ip = rd + ((size_t)b * 3136 + (2 * y) * 56 + 2 * x) * 64 + c4;
    const uint2 u00 = *(const uint2*)(ip);
    const uint2 u01 = *(const uint2*)(ip + 64);
    const uint2 u10 = *(const uint2*)(ip + 56 * 64);
    const uint2 u11 = *(const uint2*)(ip + 57 * 64);
    const unsigned short* s00 = (const unsigned short*)&u00;
    const unsigned short* s01 = (const unsigned short*)&u01;
    const unsigned short* s10 = (const unsigned short*)&u10;
    const unsigned short* s11 = (const unsigned short*)&u11;
    unsigned short ll[4], lh[4], hl[4], hh[4];
#pragma unroll
    for (int j = 0; j < 4; ++j) {
        const float a = bf2f(s00[j]), bq = bf2f(s01[j]);
        const float c = bf2f(s10[j]), d = bf2f(s11[j]);
        ll[j] = (unsigned short)f2bf((a + bq + c + d) * 0.5f);
        lh[j] = (unsigned short)f2bf((a - bq + c - d) * 0.5f);
        hl[j] = (unsigned short)f2bf((a + bq - c - d) * 0.5f);
        hh[j] = (unsigned short)f2bf((a - bq - c + d) * 0.5f);
    }
    unsigned short* op = ccl + ((size_t)b * 784 + y * 28 + x) * 256 + c4;
    *(uint2*)(op)       = make_uint2(ll[0] | (ll[1] << 16), ll[2] | (ll[3] << 16));
    *(uint2*)(op + 64)  = make_uint2(lh[0] | (lh[1] << 16), lh[2] | (lh[3] << 16));
    *(uint2*)(op + 128) = make_uint2(hl[0] | (hl[1] << 16), hl[2] | (hl[3] << 16));
    *(uint2*)(op + 192) = make_uint2(hh[0] | (hh[1] << 16), hh[2] | (hh[3] << 16));
}

// ============================== Haar IDWT -> aproj cols 256..319 ===========
// ccl2 bf16 (B,784,256) -> aproj[(b*3200+m)*320 + 256 + c], m in 56x56
__global__ __launch_bounds__(256) void idwt_k(const unsigned short* __restrict__ c2,
                                              unsigned short* __restrict__ aproj)
{
    const int i = blockIdx.x * 256 + threadIdx.x;   // 802816
    const int c4 = (i & 15) * 4;
    const int p = i >> 4;
    const int m = p % 3136, b = p / 3136;
    const int Y = m / 56, X = m - 56 * Y;
    const int y = Y >> 1, x = X >> 1;
    const unsigned short* ip = c2 + ((size_t)b * 784 + y * 28 + x) * 256 + c4;
    const uint2 ull = *(const uint2*)(ip);
    const uint2 ulh = *(const uint2*)(ip + 64);
    const uint2 uhl = *(const uint2*)(ip + 128);
    const uint2 uhh = *(const uint2*)(ip + 192);
    const unsigned short* sll = (const unsigned short*)&ull;
    const unsigned short* slh = (const unsigned short*)&ulh;
    const unsigned short* shl = (const unsigned short*)&uhl;
    const unsigned short* shh = (const unsigned short*)&uhh;
    const float flh = (X & 1) ? -0.5f : 0.5f;
    const float fhl = (Y & 1) ? -0.5f : 0.5f;
    const float fhh = ((X ^ Y) & 1) ? -0.5f : 0.5f;
    unsigned short o[4];
#pragma unroll
    for (int j = 0; j < 4; ++j) {
        const float v = 0.5f * bf2f(sll[j]) + flh * bf2f(slh[j]) +
                        fhl * bf2f(shl[j]) + fhh * bf2f(shh[j]);
        o[j] = (unsigned short)f2bf(v);
    }
    *(uint2*)(aproj + ((size_t)b * 3200 + m) * 320 + 256 + c4) =
        make_uint2(o[0] | (o[1] << 16), o[2] | (o[3] << 16));
}

// ============================== LayerNorm -> bf16, pad rows ================
__global__ __launch_bounds__(256) void ln_k(const float* __restrict__ in,
                                            const float* __restrict__ g,
                                            const float* __restrict__ bb,
                                            unsigned short* __restrict__ outp)
{
    const int rg = blockIdx.x;            // 0..4095
    const int rl = rg & 255, b = rg >> 8;
    const int t = threadIdx.x;
    unsigned short* op = outp + (size_t)rg * 256 + t;
    if (rl >= 196) { *op = 0; return; }
    const float x = in[((size_t)(b * 196) + rl) * 256 + t];
    __shared__ float r1[4], r2[4];
    float s = x;
#pragma unroll
    for (int o = 32; o > 0; o >>= 1) s += __shfl_down(s, o);
    if ((t & 63) == 0) r1[t >> 6] = s;
    __syncthreads();
    const float mu = (r1[0] + r1[1] + r1[2] + r1[3]) * (1.f / 256.f);
    const float d = x - mu;
    float s2 = d * d;
#pragma unroll
    for (int o = 32; o > 0; o >>= 1) s2 += __shfl_down(s2, o);
    if ((t & 63) == 0) r2[t >> 6] = s2;
    __syncthreads();
    const float var = (r2[0] + r2[1] + r2[2] + r2[3]) * (1.f / 256.f);
    *op = (unsigned short)f2bf(d * rsqrtf(var + 1e-5f) * g[t] + bb[t]);
}

// ============================== MFMA attention =============================
__global__ __launch_bounds__(256) void attn_m(
    const unsigned short* __restrict__ qb, const unsigned short* __restrict__ kb,
    const unsigned short* __restrict__ vt, unsigned short* __restrict__ aproj)
{
    __shared__ short Pl[4][16][232];
    const int tid = threadIdx.x, lane = tid & 63, w = tid >> 6;
    const int bh = blockIdx.y, b = bh >> 3, h = bh & 7;
    const int q0 = blockIdx.x * 64 + w * 16;
    const int cl = lane & 15, hi = lane >> 4;

    const bf16x8 qf = *(const bf16x8*)(qb + ((size_t)bh * 3136 + q0 + cl) * 32 + hi * 8);

    f32x4 s[13];
    const unsigned short* kp = kb + (size_t)bh * 224 * 32;
#pragma unroll
    for (int t = 0; t < 13; ++t) {
        const bf16x8 kf = *(const bf16x8*)(kp + (size_t)(t * 16 + cl) * 32 + hi * 8);
        s[t] = __builtin_amdgcn_mfma_f32_16x16x32_bf16(kf, qf,
                                                       (f32x4){0.f, 0.f, 0.f, 0.f}, 0, 0, 0);
    }
    if (hi) s[12] = (f32x4){-1e30f, -1e30f, -1e30f, -1e30f};

    float m = s[0][0];
#pragma unroll
    for (int t = 0; t < 13; ++t)
#pragma unroll
        for (int r = 0; r < 4; ++r) m = fmaxf(m, s[t][r]);
    m = fmaxf(m, __shfl_xor(m, 16));
    m = fmaxf(m, __shfl_xor(m, 32));

    float l = 0.f;
#pragma unroll
    for (int t = 0; t < 13; ++t) {
#pragma unroll
        for (int r = 0; r < 4; ++r) { s[t][r] = __expf(s[t][r] - m); l += s[t][r]; }
    }
    l += __shfl_xor(l, 16);
    l += __shfl_xor(l, 32);
    const float rl = 1.f / l;

    short* prow = &Pl[w][cl][0];
#pragma unroll
    for (int t = 0; t < 13; ++t) {
        __hip_bfloat162 pa = __float22bfloat162_rn(make_float2(s[t][0] * rl, s[t][1] * rl));
        __hip_bfloat162 pb = __float22bfloat162_rn(make_float2(s[t][2] * rl, s[t][3] * rl));
        unsigned int ua, ub;
        __builtin_memcpy(&ua, &pa, 4);
        __builtin_memcpy(&ub, &pb, 4);
        *(uint2*)(prow + t * 16 + hi * 4) = make_uint2(ua, ub);
    }
    *(uint2*)(prow + 208 + hi * 4) = make_uint2(0u, 0u);

    f32x4 o0 = (f32x4){0.f, 0.f, 0.f, 0.f};
    f32x4 o1 = (f32x4){0.f, 0.f, 0.f, 0.f};
    const unsigned short* vp0 = vt + ((size_t)bh * 32 + cl) * 224;
    const unsigned short* vp1 = vp0 + 16 * 224;
#pragma unroll
    for (int kk = 0; kk < 7; ++kk) {
        const bf16x8 pf = *(const bf16x8*)(prow + kk * 32 + hi * 8);
        const bf16x8 v0 = *(const bf16x8*)(vp0 + kk * 32 + hi * 8);
        const bf16x8 v1 = *(const bf16x8*)(vp1 + kk * 32 + hi * 8);
        o0 = __builtin_amdgcn_mfma_f32_16x16x32_bf16(pf, v0, o0, 0, 0, 0);
        o1 = __builtin_amdgcn_mfma_f32_16x16x32_bf16(pf, v1, o1, 0, 0, 0);
    }

    float* ol = (float*)&Pl[w][0][0];
#pragma unroll
    for (int r = 0; r < 4; ++r) {
        ol[(hi * 4 + r) * 32 + cl] = o0[r];
        ol[(hi * 4 + r) * 32 + cl + 16] = o1[r];
    }
    const int row = lane >> 2, c8 = (lane & 3) * 8;
    const float4 a0 = *(const float4*)(ol + row * 32 + c8);
    const float4 a1 = *(const float4*)(ol + row * 32 + c8 + 4);
    const unsigned int k0 = f2bf(a0.x) | (f2bf(a0.y) << 16);
    const unsigned int k1 = f2bf(a0.z) | (f2bf(a0.w) << 16);
    const unsigned int k2 = f2bf(a1.x) | (f2bf(a1.y) << 16);
    const unsigned int k3 = f2bf(a1.z) | (f2bf(a1.w) << 16);
    *(uint4*)(aproj + ((size_t)b * 3200 + q0 + row) * 320 + h * 32 + c8) =
        make_uint4(k0, k1, k2, k3);
}

// ============================== launcher ===================================
extern "C" void kernel_launch(void* const* d_in, const int* in_sizes, int n_in,
                              void* d_out, int out_size, void* d_ws, size_t ws_size,
                              hipStream_t stream)
{
    const float* x        = (const float*)d_in[0];
    const float* reduce_w = (const float*)d_in[3];
    const float* bn1_g    = (const float*)d_in[4];
    const float* bn1_b    = (const float*)d_in[5];
    const float* bn1_m    = (const float*)d_in[6];
    const float* bn1_v    = (const float*)d_in[7];
    const float* filt_w   = (const float*)d_in[8];
    const float* bn2_g    = (const float*)d_in[9];
    const float* bn2_b    = (const float*)d_in[10];
    const float* bn2_m    = (const float*)d_in[11];
    const float* bn2_v    = (const float*)d_in[12];
    const float* kve_w    = (const float*)d_in[13];
    const float* kve_b    = (const float*)d_in[14];
    const float* q_w      = (const float*)d_in[15];
    const float* q_b      = (const float*)d_in[16];
    const float* kvn_g    = (const float*)d_in[17];
    const float* kvn_b    = (const float*)d_in[18];
    const float* kv_w     = (const float*)d_in[19];
    const float* kv_b     = (const float*)d_in[20];
    const float* proj_w   = (const float*)d_in[21];
    const float* proj_b   = (const float*)d_in[22];

    float* out = (float*)d_out;
    float* ws  = (float*)d_ws;

    // ws layout (f32 units)
    unsigned short* aproj = (unsigned short*)ws;               // 16,384,000 us
    unsigned short* rd_cl = (unsigned short*)(ws +  8192000);  //  3,211,264 us
    unsigned short* ccl   = (unsigned short*)(ws +  9797632);  //  3,211,264 us
    unsigned short* ccl2  = (unsigned short*)(ws + 11403264);  //  3,211,264 us
    float* kv_src         = ws + 13008896;                     //    802,816 f
    unsigned short* kbuf  = (unsigned short*)(ws + 13811712);  //    917,504 us
    unsigned short* vtb   = (unsigned short*)(ws + 14270464);  //    917,504 us
    unsigned short* kv_ln = (unsigned short*)(ws + 14729216);  //  1,048,576 us
    unsigned short* wpl   = (unsigned short*)(ws + 15253504);  //    294,912 us
    unsigned short* wkve  = (unsigned short*)(ws + 15400960);  //    262,144 us
    unsigned short* wfilt = (unsigned short*)(ws + 15532032);  //    589,824 us
    unsigned short* wq    = wpl;
    unsigned short* wred  = wpl + 65536;
    unsigned short* wkv   = wpl + 81920;
    unsigned short* wproj = wpl + 212992;
    unsigned short* qb    = (unsigned short*)d_out;  // bf16 Q lives in d_out

    const float scale = 0.17677669529663689f; // 1/sqrt(32)

    wcvt_k<<<288, 256, 0, stream>>>(q_w, reduce_w, kv_w, proj_w, wpl);
    wcvt2_k<<<256, 256, 0, stream>>>(kve_w, wkve);
    wcvt3_k<<<576, 256, 0, stream>>>(filt_w, wfilt);

    // q = (x @ q_w^T + q_b)*scale -> qb bf16 (B,8,3136,32) in d_out
    mgemm<128, 128, 1, 2><<<dim3(25, 2, B_), 256, 0, stream>>>(
        nullptr, x, nullptr, wq, q_b, nullptr, nullptr, nullptr, nullptr,
        out, nullptr, 3136, 3136, 256, 256, scale);

    // reduced = relu(bn1(x @ reduce_w^T)) -> rd_cl bf16 channel-last (B,3136,64)
    mgemm<128, 64, 4, 2><<<dim3(25, 1, B_), 256, 0, stream>>>(
        nullptr, x, nullptr, wred, nullptr, bn1_g, bn1_b, bn1_m, bn1_v,
        (float*)rd_cl, nullptr, 3136, 3136, 64, 256, 0.f);

    // coeffs = dwt(reduced) -> ccl bf16 channel-last (B,784,256)
    dwt_k<<<784, 256, 0, stream>>>(rd_cl, ccl);

    // coeffs2 = relu(bn2(conv3x3(coeffs))) -> ccl2 bf16 channel-last
    mgemm<64, 64, 4, 1><<<dim3(13, 4, B_), 256, 0, stream>>>(
        nullptr, nullptr, ccl, wfilt, nullptr, bn2_g, bn2_b, bn2_m, bn2_v,
        (float*)ccl2, nullptr, 832, 784, 256, 2304, 0.f);

    // local = idwt(coeffs2) -> aproj cols 256..319 (bf16)
    idwt_k<<<3136, 256, 0, stream>>>(ccl2, aproj);

    // kv_src = conv2x2s2(coeffs2) + kve_b -> (B,196,256) f32 (implicit im2col)
    mgemm<64, 64, 0, 3><<<dim3(4, 4, B_), 256, 0, stream>>>(
        nullptr, nullptr, ccl2, wkve, kve_b, nullptr, nullptr, nullptr, nullptr,
        kv_src, nullptr, 256, 196, 256, 1024, 0.f);

    // layernorm -> kv_ln (B,256,256) bf16, zero pad rows
    ln_k<<<4096, 256, 0, stream>>>(kv_src, kvn_g, kvn_b, kv_ln);

    // kv: K bf16 (B,8,224,32), V^T bf16 (B,8,32,224)
    mgemm<64, 128, 3, 0><<<dim3(4, 4, B_), 256, 0, stream>>>(
        kv_ln, nullptr, nullptr, wkv, kv_b, nullptr, nullptr, nullptr, nullptr,
        (float*)kbuf, (float*)vtb, 256, 196, 512, 256, 0.f);

    // MFMA attention -> aproj cols 0..255 (bf16)
    attn_m<<<dim3(49, 128), 256, 0, stream>>>(qb, kbuf, vtb, aproj);

    // out = concat(att, local) @ proj_w^T + proj_b -> (B,3136,256) f32
    mgemm<128, 128, 0, 0><<<dim3(25, 2, B_), 256, 0, stream>>>(
        aproj, nullptr, nullptr, wproj, proj_b, nullptr, nullptr, nullptr, nullptr,
        out, nullptr, 3200, 3136, 256, 320, 0.f);
}